// Round 17
// baseline (253.071 us; speedup 1.0000x reference)
//
#include <hip/hip_runtime.h>
#include <hip/hip_fp16.h>

constexpr int FIN   = 128;   // input features (also total hidden width)
constexpr int HH    = 64;    // half hidden (GCN branch width)
constexpr int NPB   = 256;   // nodes per bucket (bucket = col >> 8)
constexpr int MAXNB = 512;   // max buckets supported (N <= 131072)
constexpr int BCH   = 4096;  // edges per k_bin block
constexpr int BCAP  = 4608;  // bucket stride in binned[]
constexpr int CAPB  = 4500;  // LDS stage capacity in k_place

typedef _Float16 half4v __attribute__((ext_vector_type(4)));

// ------------------------------------------------------------------ GEMM ----
// xwh[N,128] = fp16( x[N,128] @ [W1 | Wf1] )
__global__ __launch_bounds__(256) void k_gemm(
    const float* __restrict__ x, const float* __restrict__ W1,
    const float* __restrict__ Wf1, _Float16* __restrict__ xwh, int N)
{
    __shared__ float xs[16][68];     // [k][node], +4 pad
    __shared__ float ws[16][128];    // [k][col]

    const int tid = threadIdx.x;
    const int tx  = tid & 31;
    const int ty  = tid >> 5;
    const int nbase = blockIdx.x * 64;

    float acc[8][4];
#pragma unroll
    for (int i = 0; i < 8; ++i)
#pragma unroll
        for (int j = 0; j < 4; ++j) acc[i][j] = 0.0f;

    const int xr_row = tid >> 2;
    const int xr_kk0 = (tid & 3) * 4;
    int nload = nbase + xr_row;
    const int nclamped = (nload < N) ? nload : (N - 1);

    const int wk = tid >> 4;
    const int wc = (tid * 8) & 127;

    for (int k0 = 0; k0 < FIN; k0 += 16) {
        float4 xv = *(const float4*)(x + (size_t)nclamped * FIN + k0 + xr_kk0);
        xs[xr_kk0 + 0][xr_row] = xv.x;
        xs[xr_kk0 + 1][xr_row] = xv.y;
        xs[xr_kk0 + 2][xr_row] = xv.z;
        xs[xr_kk0 + 3][xr_row] = xv.w;
        {
            const float* src = (wc < HH) ? (W1  + (size_t)(k0 + wk) * HH + wc)
                                         : (Wf1 + (size_t)(k0 + wk) * HH + (wc - HH));
            float4 w0 = *(const float4*)(src);
            float4 w1 = *(const float4*)(src + 4);
            *(float4*)&ws[wk][wc]     = w0;
            *(float4*)&ws[wk][wc + 4] = w1;
        }
        __syncthreads();

#pragma unroll
        for (int kk = 0; kk < 16; ++kk) {
            float4 xa = *(const float4*)&xs[kk][ty * 8];
            float4 xb = *(const float4*)&xs[kk][ty * 8 + 4];
            float4 wv = *(const float4*)&ws[kk][tx * 4];
            float xr[8] = {xa.x, xa.y, xa.z, xa.w, xb.x, xb.y, xb.z, xb.w};
#pragma unroll
            for (int i = 0; i < 8; ++i) {
                acc[i][0] = fmaf(xr[i], wv.x, acc[i][0]);
                acc[i][1] = fmaf(xr[i], wv.y, acc[i][1]);
                acc[i][2] = fmaf(xr[i], wv.z, acc[i][2]);
                acc[i][3] = fmaf(xr[i], wv.w, acc[i][3]);
            }
        }
        __syncthreads();
    }

#pragma unroll
    for (int i = 0; i < 8; ++i) {
        int n = nbase + ty * 8 + i;
        if (n < N) {
            half4v h;
            h[0] = (_Float16)acc[i][0]; h[1] = (_Float16)acc[i][1];
            h[2] = (_Float16)acc[i][2]; h[3] = (_Float16)acc[i][3];
            *(half4v*)(xwh + (size_t)n * FIN + tx * 4) = h;
        }
    }
}

// --------------------------------------- pass A: bin edges by bucket --------
__global__ __launch_bounds__(256) void k_bin(
    const int* __restrict__ ei, int* __restrict__ bcur,
    int2* __restrict__ binned, int E, int NB)
{
    __shared__ int hist[MAXNB], scur[MAXNB], gbase[MAXNB], sbase[MAXNB];
    __shared__ int ssum[256];
    __shared__ int2 st[BCH];
    const int tid = threadIdx.x;
    const int e0  = blockIdx.x * BCH;
    const int nE  = min(BCH, E - e0);

    for (int b = tid; b < NB; b += 256) hist[b] = 0;
    __syncthreads();

    for (int k = tid; k < nE; k += 256)
        atomicAdd(&hist[ei[E + e0 + k] >> 8], 1);
    __syncthreads();

    // exclusive scan hist -> sbase (2 elems/thread over padded 512)
    int h0 = (2 * tid     < NB) ? hist[2 * tid]     : 0;
    int h1 = (2 * tid + 1 < NB) ? hist[2 * tid + 1] : 0;
    ssum[tid] = h0 + h1;
    __syncthreads();
    for (int o = 1; o < 256; o <<= 1) {
        int y = (tid >= o) ? ssum[tid - o] : 0;
        __syncthreads();
        ssum[tid] += y;
        __syncthreads();
    }
    int eb = ssum[tid] - h0 - h1;
    if (2 * tid     < NB) { sbase[2 * tid]     = eb;      scur[2 * tid]     = eb; }
    if (2 * tid + 1 < NB) { sbase[2 * tid + 1] = eb + h0; scur[2 * tid + 1] = eb + h0; }
    __syncthreads();

    // claim global per-bucket ranges (one atomic per non-empty bucket)
    for (int b = tid; b < NB; b += 256)
        if (hist[b] > 0) gbase[b] = atomicAdd(bcur + b, hist[b]);

    // LDS reorder by bucket
    for (int k = tid; k < nE; k += 256) {
        int r = ei[e0 + k];
        int c = ei[E + e0 + k];
        int s = atomicAdd(&scur[c >> 8], 1);
        st[s] = make_int2(r, c);
    }
    __syncthreads();

    // coalesced-run flush (bucket recomputed from col)
    for (int s = tid; s < nE; s += 256) {
        int2 rc = st[s];
        int b = rc.y >> 8;
        long dest = (long)b * BCAP + gbase[b] + (s - sbase[b]);
        binned[dest] = rc;
    }
}

// ------------------- parallel scan: bucket totals -> bucket bases -----------
__global__ __launch_bounds__(256) void k_bscan(
    const int* __restrict__ bcur, int* __restrict__ bbase, int NB)
{
    __shared__ int s[256];
    const int t = threadIdx.x;
    int a = (2 * t     < NB) ? bcur[2 * t]     : 0;
    int b = (2 * t + 1 < NB) ? bcur[2 * t + 1] : 0;
    s[t] = a + b;
    __syncthreads();
    for (int o = 1; o < 256; o <<= 1) {
        int y = (t >= o) ? s[t - o] : 0;
        __syncthreads();
        s[t] += y;
        __syncthreads();
    }
    int excl = s[t] - a - b;
    if (2 * t     < NB) bbase[2 * t]     = excl;
    if (2 * t + 1 < NB) bbase[2 * t + 1] = excl + a;
}

// ---------------- pass B: per-bucket degree+scan+place, coalesced write -----
__global__ __launch_bounds__(256) void k_place(
    const int2* __restrict__ binned, const int* __restrict__ bcur,
    const int* __restrict__ bbase, int* __restrict__ cnt, int* __restrict__ off,
    float* __restrict__ dinv, int* __restrict__ sedge, int N)
{
    const int b   = blockIdx.x;
    const int tid = threadIdx.x;
    const int nlo = b << 8;
    const int nn  = min(NPB, N - nlo);
    __shared__ int lcnt[NPB], loff[NPB], lscan[NPB];
    __shared__ int stage[CAPB];
    lcnt[tid] = 0;
    __syncthreads();
    const int ke = bcur[b];
    const int2* src = binned + (long)b * BCAP;
    // pass 1: per-node degree
    for (int k = tid; k < ke; k += 256)
        atomicAdd(&lcnt[src[k].y - nlo], 1);
    __syncthreads();
    // exclusive scan of lcnt[256]
    int v = lcnt[tid];
    lscan[tid] = v;
    __syncthreads();
    for (int o = 1; o < 256; o <<= 1) {
        int y = (tid >= o) ? lscan[tid - o] : 0;
        __syncthreads();
        lscan[tid] += y;
        __syncthreads();
    }
    int excl = lscan[tid] - v;
    loff[tid] = excl;
    const int base = bbase[b];
    if (tid < nn) {
        cnt[nlo + tid]  = v;
        off[nlo + tid]  = base + excl;
        dinv[nlo + tid] = rsqrtf((float)v + 1.0f);
    }
    lcnt[tid] = 0;
    __syncthreads();
    // pass 2: place source ids
    if (ke <= CAPB) {
        for (int k = tid; k < ke; k += 256) {
            int2 rc = src[k];
            int li = rc.y - nlo;
            int p = atomicAdd(&lcnt[li], 1);
            stage[loff[li] + p] = rc.x;
        }
        __syncthreads();
        for (int s = tid; s < ke; s += 256) sedge[base + s] = stage[s];
    } else {   // statistically impossible overflow fallback
        for (int k = tid; k < ke; k += 256) {
            int2 rc = src[k];
            int li = rc.y - nlo;
            int p = atomicAdd(&lcnt[li], 1);
            sedge[base + loff[li] + p] = rc.x;
        }
    }
}

// ------------------------- fused: layer-1 aggregate + relu + layer-2 dots ---
// 4 gathers in flight per 16-lane group (step 16 edges/iter): round-15
// counters showed FETCH -22MB with dur unchanged -> latency-bound, not
// byte-bound; deepening MLP is the lever under test.
__global__ __launch_bounds__(256) void k_fused(
    const int* __restrict__ off, const int* __restrict__ cnt,
    const int* __restrict__ sedge, const float* __restrict__ dinv,
    const _Float16* __restrict__ xwh,
    const float* __restrict__ b1, const float* __restrict__ bf1,
    const float* __restrict__ W2, const float* __restrict__ Wf2,
    const float* __restrict__ b2, const float* __restrict__ bf2,
    float* __restrict__ z, float* __restrict__ out, int N)
{
    const int wid  = (blockIdx.x * blockDim.x + threadIdx.x) >> 6;  // node id
    const int lane = threadIdx.x & 63;
    const int g    = lane >> 4;        // edge group 0..3
    const int l16  = lane & 15;        // feature quad
    const int i    = (wid < N) ? wid : (N - 1);

    const int jb  = off[i];
    const int deg = cnt[i];
    const float di = dinv[i];

    int   er_r = i;
    float er_d = 0.0f;
    if (lane < deg) { er_r = sedge[jb + lane]; er_d = dinv[er_r]; }

    float4 acc = make_float4(0.f, 0.f, 0.f, 0.f);
    const int lim = (deg < 64) ? deg : 64;
    for (int t0 = 0; t0 < lim; t0 += 16) {
        int  tt0 = t0 + g,  tt1 = t0 + 4 + g,  tt2 = t0 + 8 + g,  tt3 = t0 + 12 + g;
        bool v0 = tt0 < lim, v1 = tt1 < lim, v2 = tt2 < lim, v3 = tt3 < lim;
        int   r0 = __shfl(er_r, tt0, 64);  float d0 = __shfl(er_d, tt0, 64);
        int   r1 = __shfl(er_r, tt1, 64);  float d1 = __shfl(er_d, tt1, 64);
        int   r2 = __shfl(er_r, tt2, 64);  float d2 = __shfl(er_d, tt2, 64);
        int   r3 = __shfl(er_r, tt3, 64);  float d3 = __shfl(er_d, tt3, 64);
        r0 = v0 ? r0 : i;  r1 = v1 ? r1 : i;  r2 = v2 ? r2 : i;  r3 = v3 ? r3 : i;
        float s0 = v0 ? d0 * di : 0.0f;
        float s1 = v1 ? d1 * di : 0.0f;
        float s2 = v2 ? d2 * di : 0.0f;
        float s3 = v3 ? d3 * di : 0.0f;
        // issue all four gathers before any consumption
        half4v a0 = *(const half4v*)(xwh + (size_t)r0 * FIN + l16 * 4);
        half4v a1 = *(const half4v*)(xwh + (size_t)r1 * FIN + l16 * 4);
        half4v a2 = *(const half4v*)(xwh + (size_t)r2 * FIN + l16 * 4);
        half4v a3 = *(const half4v*)(xwh + (size_t)r3 * FIN + l16 * 4);
        acc.x = fmaf((float)a0[0], s0, acc.x);
        acc.y = fmaf((float)a0[1], s0, acc.y);
        acc.z = fmaf((float)a0[2], s0, acc.z);
        acc.w = fmaf((float)a0[3], s0, acc.w);
        acc.x = fmaf((float)a1[0], s1, acc.x);
        acc.y = fmaf((float)a1[1], s1, acc.y);
        acc.z = fmaf((float)a1[2], s1, acc.z);
        acc.w = fmaf((float)a1[3], s1, acc.w);
        acc.x = fmaf((float)a2[0], s2, acc.x);
        acc.y = fmaf((float)a2[1], s2, acc.y);
        acc.z = fmaf((float)a2[2], s2, acc.z);
        acc.w = fmaf((float)a2[3], s2, acc.w);
        acc.x = fmaf((float)a3[0], s3, acc.x);
        acc.y = fmaf((float)a3[1], s3, acc.y);
        acc.z = fmaf((float)a3[2], s3, acc.z);
        acc.w = fmaf((float)a3[3], s3, acc.w);
    }
    // rare tail: deg > 64
    for (int j = jb + 64 + g; j < jb + deg; j += 4) {
        int rj = sedge[j];
        float s = dinv[rj] * di;
        half4v v = *(const half4v*)(xwh + (size_t)rj * FIN + l16 * 4);
        acc.x = fmaf((float)v[0], s, acc.x);
        acc.y = fmaf((float)v[1], s, acc.y);
        acc.z = fmaf((float)v[2], s, acc.z);
        acc.w = fmaf((float)v[3], s, acc.w);
    }

    // combine the 4 edge-groups
    acc.x += __shfl_xor(acc.x, 16, 64); acc.x += __shfl_xor(acc.x, 32, 64);
    acc.y += __shfl_xor(acc.y, 16, 64); acc.y += __shfl_xor(acc.y, 32, 64);
    acc.z += __shfl_xor(acc.z, 16, 64); acc.z += __shfl_xor(acc.z, 32, 64);
    acc.w += __shfl_xor(acc.w, 16, 64); acc.w += __shfl_xor(acc.w, 32, 64);

    // self loop (fp16 row)
    float dd = di * di;
    half4v svh = *(const half4v*)(xwh + (size_t)i * FIN + l16 * 4);
    acc.x = fmaf((float)svh[0], dd, acc.x);
    acc.y = fmaf((float)svh[1], dd, acc.y);
    acc.z = fmaf((float)svh[2], dd, acc.z);
    acc.w = fmaf((float)svh[3], dd, acc.w);

    // epilogue: relu + two 128-dots
    float4 b1v  = *(const float4*)(b1  + l16 * 4);
    float4 bf1v = *(const float4*)(bf1 + l16 * 4);
    half4v x1h  = *(const half4v*)(xwh + (size_t)i * FIN + HH + l16 * 4);
    float4 h0, h1;
    h0.x = fmaxf(acc.x + b1v.x, 0.f);  h0.y = fmaxf(acc.y + b1v.y, 0.f);
    h0.z = fmaxf(acc.z + b1v.z, 0.f);  h0.w = fmaxf(acc.w + b1v.w, 0.f);
    h1.x = fmaxf((float)x1h[0] + bf1v.x, 0.f);  h1.y = fmaxf((float)x1h[1] + bf1v.y, 0.f);
    h1.z = fmaxf((float)x1h[2] + bf1v.z, 0.f);  h1.w = fmaxf((float)x1h[3] + bf1v.w, 0.f);

    float4 w2a  = *(const float4*)(W2  + l16 * 4);
    float4 w2b  = *(const float4*)(W2  + HH + l16 * 4);
    float4 wf2a = *(const float4*)(Wf2 + l16 * 4);
    float4 wf2b = *(const float4*)(Wf2 + HH + l16 * 4);

    float zp = h0.x * w2a.x + h0.y * w2a.y + h0.z * w2a.z + h0.w * w2a.w
             + h1.x * w2b.x + h1.y * w2b.y + h1.z * w2b.z + h1.w * w2b.w;
    float fp = h0.x * wf2a.x + h0.y * wf2a.y + h0.z * wf2a.z + h0.w * wf2a.w
             + h1.x * wf2b.x + h1.y * wf2b.y + h1.z * wf2b.z + h1.w * wf2b.w;
#pragma unroll
    for (int o = 8; o > 0; o >>= 1) {
        zp += __shfl_xor(zp, o, 64);
        fp += __shfl_xor(fp, o, 64);
    }
    if (lane == 0 && wid < N) {
        z[i]   = zp;
        out[i] = fp + b2[0] + bf2[0];
    }
}

// ------------------------------------------- layer-2 aggregate (CSR) --------
// out[i] += di * ( sum_j z[r_j]*dinv[r_j]  +  z[i]*di )
__global__ __launch_bounds__(256) void k_agg2(
    const int* __restrict__ off, const int* __restrict__ cnt,
    const int* __restrict__ sedge, const float* __restrict__ dinv,
    const float* __restrict__ z, float* __restrict__ out, int N)
{
    const int wid  = (blockIdx.x * blockDim.x + threadIdx.x) >> 6;
    const int lane = threadIdx.x & 63;
    const int g    = lane >> 4;
    const int l16  = lane & 15;
    int i = wid * 4 + g;
    bool ok = (i < N);
    i = ok ? i : (N - 1);

    const int jb = off[i], je = jb + cnt[i];
    float s = 0.0f;
    for (int j = jb + l16; j < je; j += 16) {
        int r = sedge[j];
        s = fmaf(z[r], dinv[r], s);
    }
#pragma unroll
    for (int o = 8; o > 0; o >>= 1) s += __shfl_xor(s, o, 64);
    if (l16 == 0 && ok) {
        float di = dinv[i];
        out[i] += di * fmaf(z[i], di, s);
    }
}

// ---------------------------------------------------------------- launch ----
extern "C" void kernel_launch(void* const* d_in, const int* in_sizes, int n_in,
                              void* d_out, int out_size, void* d_ws, size_t ws_size,
                              hipStream_t stream)
{
    const float* x   = (const float*)d_in[0];
    const int*   ei  = (const int*)d_in[1];    // [2,E]: row=ei[e], col=ei[E+e]
    const float* W1  = (const float*)d_in[2];
    const float* b1  = (const float*)d_in[3];
    const float* Wf1 = (const float*)d_in[4];
    const float* bf1 = (const float*)d_in[5];
    const float* W2  = (const float*)d_in[6];
    const float* b2  = (const float*)d_in[7];
    const float* Wf2 = (const float*)d_in[8];
    const float* bf2 = (const float*)d_in[9];

    const int N = in_sizes[0] / FIN;   // 100000
    const int E = in_sizes[1] / 2;     // 1600000
    const int NB = (N + NPB - 1) / NPB;  // 391 buckets
    float* out = (float*)d_out;

    // workspace layout (4-byte units):
    // dinv[N] | z[N] | cnt[N] | bcur[MAXNB] | bbase[MAXNB] | off[N] |
    // sedge int[E] | xwh[N*128 halves] | binned[NB*BCAP int2]
    float* ws   = (float*)d_ws;
    float* dinv = ws;
    float* z    = dinv + N;
    int*   cnt  = (int*)(z + N);
    int*   bcur = cnt + N;
    int*   bbase = bcur + MAXNB;
    int*   off  = bbase + MAXNB;
    int*   sedge = off + N;
    _Float16* xwh = (_Float16*)(sedge + E);
    int2*  binned = (int2*)(xwh + (size_t)N * FIN);

    hipMemsetAsync(bcur, 0, (size_t)MAXNB * sizeof(int), stream);

    k_bin<<<(E + BCH - 1) / BCH, 256, 0, stream>>>(ei, bcur, binned, E, NB);
    k_bscan<<<1, 256, 0, stream>>>(bcur, bbase, NB);
    k_place<<<NB, 256, 0, stream>>>(binned, bcur, bbase, cnt, off, dinv, sedge, N);

    k_gemm<<<(N + 63) / 64, 256, 0, stream>>>(x, W1, Wf1, xwh, N);

    {
        long threads = (long)N * 64;           // one wave per node
        int blocks = (int)((threads + 255) / 256);
        k_fused<<<blocks, 256, 0, stream>>>(off, cnt, sedge, dinv, xwh,
                                            b1, bf1, W2, Wf2, b2, bf2, z, out, N);
    }

    {
        long waves = ((long)N + 3) / 4;        // one wave per 4 nodes
        int blocks = (int)((waves * 64 + 255) / 256);
        k_agg2<<<blocks, 256, 0, stream>>>(off, cnt, sedge, dinv, z, out, N);
    }
}

// Round 18
// 232.879 us; speedup vs baseline: 1.0867x; 1.0867x over previous
//
#include <hip/hip_runtime.h>
#include <hip/hip_fp16.h>

constexpr int FIN   = 128;   // input features (also total hidden width)
constexpr int HH    = 64;    // half hidden (GCN branch width)
constexpr int NPB   = 256;   // nodes per bucket (bucket = col >> 8)
constexpr int MAXNB = 512;   // max buckets supported (N <= 131072)
constexpr int BCH   = 4096;  // edges per k_bin block
constexpr int BCAP  = 4608;  // bucket stride in binned[]
constexpr int CAPB  = 4500;  // LDS stage capacity in k_place

typedef _Float16 half4v __attribute__((ext_vector_type(4)));

// ------------------------------------------------------------------ GEMM ----
// xwh[N,128] = fp16( x[N,128] @ [W1 | Wf1] )
__global__ __launch_bounds__(256) void k_gemm(
    const float* __restrict__ x, const float* __restrict__ W1,
    const float* __restrict__ Wf1, _Float16* __restrict__ xwh, int N)
{
    __shared__ float xs[16][68];     // [k][node], +4 pad
    __shared__ float ws[16][128];    // [k][col]

    const int tid = threadIdx.x;
    const int tx  = tid & 31;
    const int ty  = tid >> 5;
    const int nbase = blockIdx.x * 64;

    float acc[8][4];
#pragma unroll
    for (int i = 0; i < 8; ++i)
#pragma unroll
        for (int j = 0; j < 4; ++j) acc[i][j] = 0.0f;

    const int xr_row = tid >> 2;
    const int xr_kk0 = (tid & 3) * 4;
    int nload = nbase + xr_row;
    const int nclamped = (nload < N) ? nload : (N - 1);

    const int wk = tid >> 4;
    const int wc = (tid * 8) & 127;

    for (int k0 = 0; k0 < FIN; k0 += 16) {
        float4 xv = *(const float4*)(x + (size_t)nclamped * FIN + k0 + xr_kk0);
        xs[xr_kk0 + 0][xr_row] = xv.x;
        xs[xr_kk0 + 1][xr_row] = xv.y;
        xs[xr_kk0 + 2][xr_row] = xv.z;
        xs[xr_kk0 + 3][xr_row] = xv.w;
        {
            const float* src = (wc < HH) ? (W1  + (size_t)(k0 + wk) * HH + wc)
                                         : (Wf1 + (size_t)(k0 + wk) * HH + (wc - HH));
            float4 w0 = *(const float4*)(src);
            float4 w1 = *(const float4*)(src + 4);
            *(float4*)&ws[wk][wc]     = w0;
            *(float4*)&ws[wk][wc + 4] = w1;
        }
        __syncthreads();

#pragma unroll
        for (int kk = 0; kk < 16; ++kk) {
            float4 xa = *(const float4*)&xs[kk][ty * 8];
            float4 xb = *(const float4*)&xs[kk][ty * 8 + 4];
            float4 wv = *(const float4*)&ws[kk][tx * 4];
            float xr[8] = {xa.x, xa.y, xa.z, xa.w, xb.x, xb.y, xb.z, xb.w};
#pragma unroll
            for (int i = 0; i < 8; ++i) {
                acc[i][0] = fmaf(xr[i], wv.x, acc[i][0]);
                acc[i][1] = fmaf(xr[i], wv.y, acc[i][1]);
                acc[i][2] = fmaf(xr[i], wv.z, acc[i][2]);
                acc[i][3] = fmaf(xr[i], wv.w, acc[i][3]);
            }
        }
        __syncthreads();
    }

#pragma unroll
    for (int i = 0; i < 8; ++i) {
        int n = nbase + ty * 8 + i;
        if (n < N) {
            half4v h;
            h[0] = (_Float16)acc[i][0]; h[1] = (_Float16)acc[i][1];
            h[2] = (_Float16)acc[i][2]; h[3] = (_Float16)acc[i][3];
            *(half4v*)(xwh + (size_t)n * FIN + tx * 4) = h;
        }
    }
}

// --------------------------------------- pass A: bin edges by bucket --------
__global__ __launch_bounds__(256) void k_bin(
    const int* __restrict__ ei, int* __restrict__ bcur,
    int2* __restrict__ binned, int E, int NB)
{
    __shared__ int hist[MAXNB], scur[MAXNB], gbase[MAXNB], sbase[MAXNB];
    __shared__ int ssum[256];
    __shared__ int2 st[BCH];
    const int tid = threadIdx.x;
    const int e0  = blockIdx.x * BCH;
    const int nE  = min(BCH, E - e0);

    for (int b = tid; b < NB; b += 256) hist[b] = 0;
    __syncthreads();

    for (int k = tid; k < nE; k += 256)
        atomicAdd(&hist[ei[E + e0 + k] >> 8], 1);
    __syncthreads();

    // exclusive scan hist -> sbase (2 elems/thread over padded 512)
    int h0 = (2 * tid     < NB) ? hist[2 * tid]     : 0;
    int h1 = (2 * tid + 1 < NB) ? hist[2 * tid + 1] : 0;
    ssum[tid] = h0 + h1;
    __syncthreads();
    for (int o = 1; o < 256; o <<= 1) {
        int y = (tid >= o) ? ssum[tid - o] : 0;
        __syncthreads();
        ssum[tid] += y;
        __syncthreads();
    }
    int eb = ssum[tid] - h0 - h1;
    if (2 * tid     < NB) { sbase[2 * tid]     = eb;      scur[2 * tid]     = eb; }
    if (2 * tid + 1 < NB) { sbase[2 * tid + 1] = eb + h0; scur[2 * tid + 1] = eb + h0; }
    __syncthreads();

    // claim global per-bucket ranges (one atomic per non-empty bucket)
    for (int b = tid; b < NB; b += 256)
        if (hist[b] > 0) gbase[b] = atomicAdd(bcur + b, hist[b]);

    // LDS reorder by bucket
    for (int k = tid; k < nE; k += 256) {
        int r = ei[e0 + k];
        int c = ei[E + e0 + k];
        int s = atomicAdd(&scur[c >> 8], 1);
        st[s] = make_int2(r, c);
    }
    __syncthreads();

    // coalesced-run flush (bucket recomputed from col)
    for (int s = tid; s < nE; s += 256) {
        int2 rc = st[s];
        int b = rc.y >> 8;
        long dest = (long)b * BCAP + gbase[b] + (s - sbase[b]);
        binned[dest] = rc;
    }
}

// ------------------- parallel scan: bucket totals -> bucket bases -----------
__global__ __launch_bounds__(256) void k_bscan(
    const int* __restrict__ bcur, int* __restrict__ bbase, int NB)
{
    __shared__ int s[256];
    const int t = threadIdx.x;
    int a = (2 * t     < NB) ? bcur[2 * t]     : 0;
    int b = (2 * t + 1 < NB) ? bcur[2 * t + 1] : 0;
    s[t] = a + b;
    __syncthreads();
    for (int o = 1; o < 256; o <<= 1) {
        int y = (t >= o) ? s[t - o] : 0;
        __syncthreads();
        s[t] += y;
        __syncthreads();
    }
    int excl = s[t] - a - b;
    if (2 * t     < NB) bbase[2 * t]     = excl;
    if (2 * t + 1 < NB) bbase[2 * t + 1] = excl + a;
}

// ---------------- pass B: per-bucket degree+scan+place, coalesced write -----
__global__ __launch_bounds__(256) void k_place(
    const int2* __restrict__ binned, const int* __restrict__ bcur,
    const int* __restrict__ bbase, int* __restrict__ cnt, int* __restrict__ off,
    float* __restrict__ dinv, int* __restrict__ sedge, int N)
{
    const int b   = blockIdx.x;
    const int tid = threadIdx.x;
    const int nlo = b << 8;
    const int nn  = min(NPB, N - nlo);
    __shared__ int lcnt[NPB], loff[NPB], lscan[NPB];
    __shared__ int stage[CAPB];
    lcnt[tid] = 0;
    __syncthreads();
    const int ke = bcur[b];
    const int2* src = binned + (long)b * BCAP;
    // pass 1: per-node degree
    for (int k = tid; k < ke; k += 256)
        atomicAdd(&lcnt[src[k].y - nlo], 1);
    __syncthreads();
    // exclusive scan of lcnt[256]
    int v = lcnt[tid];
    lscan[tid] = v;
    __syncthreads();
    for (int o = 1; o < 256; o <<= 1) {
        int y = (tid >= o) ? lscan[tid - o] : 0;
        __syncthreads();
        lscan[tid] += y;
        __syncthreads();
    }
    int excl = lscan[tid] - v;
    loff[tid] = excl;
    const int base = bbase[b];
    if (tid < nn) {
        cnt[nlo + tid]  = v;
        off[nlo + tid]  = base + excl;
        dinv[nlo + tid] = rsqrtf((float)v + 1.0f);
    }
    lcnt[tid] = 0;
    __syncthreads();
    // pass 2: place source ids
    if (ke <= CAPB) {
        for (int k = tid; k < ke; k += 256) {
            int2 rc = src[k];
            int li = rc.y - nlo;
            int p = atomicAdd(&lcnt[li], 1);
            stage[loff[li] + p] = rc.x;
        }
        __syncthreads();
        for (int s = tid; s < ke; s += 256) sedge[base + s] = stage[s];
    } else {   // statistically impossible overflow fallback
        for (int k = tid; k < ke; k += 256) {
            int2 rc = src[k];
            int li = rc.y - nlo;
            int p = atomicAdd(&lcnt[li], 1);
            sedge[base + loff[li] + p] = rc.x;
        }
    }
}

// ------------------------- fused: layer-1 aggregate + relu + layer-2 dots ---
// 4 NODES PER WAVE (one per 16-lane group): rounds 15/17 falsified byte- and
// latency-bound theories; per-node fixed cost (shfl machinery, cross-group
// combine, 8 float4 weight loads) dominated at 1 node/wave. Now: lane owns
// features l16*4..+3 of its group's node across ALL edges (no combine);
// edge id + dinv come from same-address broadcast loads; epilogue weight
// registers (l16-indexed) are shared by all 4 nodes.
__global__ __launch_bounds__(256) void k_fused(
    const int* __restrict__ off, const int* __restrict__ cnt,
    const int* __restrict__ sedge, const float* __restrict__ dinv,
    const _Float16* __restrict__ xwh,
    const float* __restrict__ b1, const float* __restrict__ bf1,
    const float* __restrict__ W2, const float* __restrict__ Wf2,
    const float* __restrict__ b2, const float* __restrict__ bf2,
    float* __restrict__ z, float* __restrict__ out, int N)
{
    const int wv   = (blockIdx.x * blockDim.x + threadIdx.x) >> 6;  // wave id
    const int lane = threadIdx.x & 63;
    const int g    = lane >> 4;        // node slot 0..3
    const int l16  = lane & 15;        // feature quad: features l16*4..+3
    int i = wv * 4 + g;
    const bool ok = (i < N);
    i = ok ? i : (N - 1);

    const int jb  = off[i];
    const int deg = cnt[i];
    const float di = dinv[i];

    float4 acc = make_float4(0.f, 0.f, 0.f, 0.f);
    int j = 0;
    for (; j + 4 <= deg; j += 4) {   // 4 gathers in flight per group
        int r0 = sedge[jb + j];
        int r1 = sedge[jb + j + 1];
        int r2 = sedge[jb + j + 2];
        int r3 = sedge[jb + j + 3];
        float s0 = dinv[r0] * di;
        float s1 = dinv[r1] * di;
        float s2 = dinv[r2] * di;
        float s3 = dinv[r3] * di;
        half4v a0 = *(const half4v*)(xwh + (size_t)r0 * FIN + l16 * 4);
        half4v a1 = *(const half4v*)(xwh + (size_t)r1 * FIN + l16 * 4);
        half4v a2 = *(const half4v*)(xwh + (size_t)r2 * FIN + l16 * 4);
        half4v a3 = *(const half4v*)(xwh + (size_t)r3 * FIN + l16 * 4);
        acc.x = fmaf((float)a0[0], s0, acc.x);
        acc.y = fmaf((float)a0[1], s0, acc.y);
        acc.z = fmaf((float)a0[2], s0, acc.z);
        acc.w = fmaf((float)a0[3], s0, acc.w);
        acc.x = fmaf((float)a1[0], s1, acc.x);
        acc.y = fmaf((float)a1[1], s1, acc.y);
        acc.z = fmaf((float)a1[2], s1, acc.z);
        acc.w = fmaf((float)a1[3], s1, acc.w);
        acc.x = fmaf((float)a2[0], s2, acc.x);
        acc.y = fmaf((float)a2[1], s2, acc.y);
        acc.z = fmaf((float)a2[2], s2, acc.z);
        acc.w = fmaf((float)a2[3], s2, acc.w);
        acc.x = fmaf((float)a3[0], s3, acc.x);
        acc.y = fmaf((float)a3[1], s3, acc.y);
        acc.z = fmaf((float)a3[2], s3, acc.z);
        acc.w = fmaf((float)a3[3], s3, acc.w);
    }
    for (; j < deg; ++j) {
        int r = sedge[jb + j];
        float s = dinv[r] * di;
        half4v a = *(const half4v*)(xwh + (size_t)r * FIN + l16 * 4);
        acc.x = fmaf((float)a[0], s, acc.x);
        acc.y = fmaf((float)a[1], s, acc.y);
        acc.z = fmaf((float)a[2], s, acc.z);
        acc.w = fmaf((float)a[3], s, acc.w);
    }

    // self loop (fp16 row) — no cross-lane combine needed in this layout
    float dd = di * di;
    half4v svh = *(const half4v*)(xwh + (size_t)i * FIN + l16 * 4);
    acc.x = fmaf((float)svh[0], dd, acc.x);
    acc.y = fmaf((float)svh[1], dd, acc.y);
    acc.z = fmaf((float)svh[2], dd, acc.z);
    acc.w = fmaf((float)svh[3], dd, acc.w);

    // epilogue: relu + two 128-dots (weights l16-indexed: shared by 4 nodes)
    float4 b1v  = *(const float4*)(b1  + l16 * 4);
    float4 bf1v = *(const float4*)(bf1 + l16 * 4);
    half4v x1h  = *(const half4v*)(xwh + (size_t)i * FIN + HH + l16 * 4);
    float4 h0, h1;
    h0.x = fmaxf(acc.x + b1v.x, 0.f);  h0.y = fmaxf(acc.y + b1v.y, 0.f);
    h0.z = fmaxf(acc.z + b1v.z, 0.f);  h0.w = fmaxf(acc.w + b1v.w, 0.f);
    h1.x = fmaxf((float)x1h[0] + bf1v.x, 0.f);  h1.y = fmaxf((float)x1h[1] + bf1v.y, 0.f);
    h1.z = fmaxf((float)x1h[2] + bf1v.z, 0.f);  h1.w = fmaxf((float)x1h[3] + bf1v.w, 0.f);

    float4 w2a  = *(const float4*)(W2  + l16 * 4);
    float4 w2b  = *(const float4*)(W2  + HH + l16 * 4);
    float4 wf2a = *(const float4*)(Wf2 + l16 * 4);
    float4 wf2b = *(const float4*)(Wf2 + HH + l16 * 4);

    float zp = h0.x * w2a.x + h0.y * w2a.y + h0.z * w2a.z + h0.w * w2a.w
             + h1.x * w2b.x + h1.y * w2b.y + h1.z * w2b.z + h1.w * w2b.w;
    float fp = h0.x * wf2a.x + h0.y * wf2a.y + h0.z * wf2a.z + h0.w * wf2a.w
             + h1.x * wf2b.x + h1.y * wf2b.y + h1.z * wf2b.z + h1.w * wf2b.w;
#pragma unroll
    for (int o = 8; o > 0; o >>= 1) {
        zp += __shfl_xor(zp, o, 16);   // reduce within the 16-lane group
        fp += __shfl_xor(fp, o, 16);
    }
    if (l16 == 0 && ok) {
        z[i]   = zp;
        out[i] = fp + b2[0] + bf2[0];
    }
}

// ------------------------------------------- layer-2 aggregate (CSR) --------
// out[i] += di * ( sum_j z[r_j]*dinv[r_j]  +  z[i]*di )
__global__ __launch_bounds__(256) void k_agg2(
    const int* __restrict__ off, const int* __restrict__ cnt,
    const int* __restrict__ sedge, const float* __restrict__ dinv,
    const float* __restrict__ z, float* __restrict__ out, int N)
{
    const int wid  = (blockIdx.x * blockDim.x + threadIdx.x) >> 6;
    const int lane = threadIdx.x & 63;
    const int g    = lane >> 4;
    const int l16  = lane & 15;
    int i = wid * 4 + g;
    bool ok = (i < N);
    i = ok ? i : (N - 1);

    const int jb = off[i], je = jb + cnt[i];
    float s = 0.0f;
    for (int j = jb + l16; j < je; j += 16) {
        int r = sedge[j];
        s = fmaf(z[r], dinv[r], s);
    }
#pragma unroll
    for (int o = 8; o > 0; o >>= 1) s += __shfl_xor(s, o, 64);
    if (l16 == 0 && ok) {
        float di = dinv[i];
        out[i] += di * fmaf(z[i], di, s);
    }
}

// ---------------------------------------------------------------- launch ----
extern "C" void kernel_launch(void* const* d_in, const int* in_sizes, int n_in,
                              void* d_out, int out_size, void* d_ws, size_t ws_size,
                              hipStream_t stream)
{
    const float* x   = (const float*)d_in[0];
    const int*   ei  = (const int*)d_in[1];    // [2,E]: row=ei[e], col=ei[E+e]
    const float* W1  = (const float*)d_in[2];
    const float* b1  = (const float*)d_in[3];
    const float* Wf1 = (const float*)d_in[4];
    const float* bf1 = (const float*)d_in[5];
    const float* W2  = (const float*)d_in[6];
    const float* b2  = (const float*)d_in[7];
    const float* Wf2 = (const float*)d_in[8];
    const float* bf2 = (const float*)d_in[9];

    const int N = in_sizes[0] / FIN;   // 100000
    const int E = in_sizes[1] / 2;     // 1600000
    const int NB = (N + NPB - 1) / NPB;  // 391 buckets
    float* out = (float*)d_out;

    // workspace layout (4-byte units):
    // dinv[N] | z[N] | cnt[N] | bcur[MAXNB] | bbase[MAXNB] | off[N] |
    // sedge int[E] | xwh[N*128 halves] | binned[NB*BCAP int2]
    float* ws   = (float*)d_ws;
    float* dinv = ws;
    float* z    = dinv + N;
    int*   cnt  = (int*)(z + N);
    int*   bcur = cnt + N;
    int*   bbase = bcur + MAXNB;
    int*   off  = bbase + MAXNB;
    int*   sedge = off + N;
    _Float16* xwh = (_Float16*)(sedge + E);
    int2*  binned = (int2*)(xwh + (size_t)N * FIN);

    hipMemsetAsync(bcur, 0, (size_t)MAXNB * sizeof(int), stream);

    k_bin<<<(E + BCH - 1) / BCH, 256, 0, stream>>>(ei, bcur, binned, E, NB);
    k_bscan<<<1, 256, 0, stream>>>(bcur, bbase, NB);
    k_place<<<NB, 256, 0, stream>>>(binned, bcur, bbase, cnt, off, dinv, sedge, N);

    k_gemm<<<(N + 63) / 64, 256, 0, stream>>>(x, W1, Wf1, xwh, N);

    {
        long waves = ((long)N + 3) / 4;        // one wave per 4 nodes
        int blocks = (int)((waves * 64 + 255) / 256);
        k_fused<<<blocks, 256, 0, stream>>>(off, cnt, sedge, dinv, xwh,
                                            b1, bf1, W2, Wf2, b2, bf2, z, out, N);
    }

    {
        long waves = ((long)N + 3) / 4;        // one wave per 4 nodes
        int blocks = (int)((waves * 64 + 255) / 256);
        k_agg2<<<blocks, 256, 0, stream>>>(off, cnt, sedge, dinv, z, out, N);
    }
}

// Round 19
// 212.901 us; speedup vs baseline: 1.1887x; 1.0938x over previous
//
#include <hip/hip_runtime.h>
#include <hip/hip_fp16.h>

constexpr int FIN   = 128;   // input features (also total hidden width)
constexpr int HH    = 64;    // half hidden (GCN branch width)
constexpr int NPB   = 256;   // nodes per bucket (bucket = col >> 8)
constexpr int MAXNB = 512;   // max buckets supported (N <= 131072)
constexpr int BCH   = 4096;  // edges per k_bin block
constexpr int BCAP  = 4608;  // bucket stride in binned[]
constexpr int CAPB  = 4500;  // LDS stage capacity in k_place

typedef _Float16 half4v __attribute__((ext_vector_type(4)));
typedef _Float16 half8v __attribute__((ext_vector_type(8)));
typedef float    f32x4 __attribute__((ext_vector_type(4)));

// ------------------------------------------------------------------ GEMM ----
// MFMA version: xwh[N,128] = fp16( x @ [W1|Wf1] ), fp32 accumulate.
// Round-18 counters: vector GEMM was LDS-read-bound (384 ds_read_b128/thread,
// 1.2M bank conflicts, 47us of LDS-pipe time). MFMA cuts LDS traffic to
// 32 b128/wave (B frags; A comes straight from global w/ cvt) -> streaming.
// Per wave: 16 rows x 128 cols, K=128 = 8 col-tiles x 4 K-steps of
// v_mfma_f32_16x16x32_f16. W staged once/block as transposed fp16 tile,
// XOR-swizzled (granule ^= n&7) for ~2-way banks.
__global__ __launch_bounds__(256) void k_gemm(
    const float* __restrict__ x, const float* __restrict__ W1,
    const float* __restrict__ Wf1, _Float16* __restrict__ xwh, int N)
{
    __shared__ _Float16 wt[128 * 128];   // wt[n][k] swizzled, 32KB

    const int tid = threadIdx.x;
    // stage W^T fp16 (coalesced fp32 reads: consecutive tid -> consecutive n)
    for (int idx = tid; idx < 128 * 128; idx += 256) {
        int n = idx & 127, k = idx >> 7;
        float v = (n < HH) ? W1[k * HH + n] : Wf1[k * HH + (n - HH)];
        int g  = k >> 3, j = k & 7;
        int pg = g ^ (n & 7);                    // bank swizzle
        wt[n * 128 + pg * 8 + j] = (_Float16)v;
    }
    __syncthreads();

    const int w  = tid >> 6;                     // wave 0..3
    const int l  = tid & 63;
    const int rb = blockIdx.x * 64 + w * 16;     // this wave's 16 rows

    // A fragments: row = l&15, k = ks*32 + (l>>4)*8 + j  (global fp32 -> fp16)
    int arow = rb + (l & 15);
    arow = (arow < N) ? arow : (N - 1);
    half8v af[4];
#pragma unroll
    for (int ks = 0; ks < 4; ++ks) {
        const float* src = x + (size_t)arow * FIN + ks * 32 + (l >> 4) * 8;
        float4 x0 = *(const float4*)(src);
        float4 x1 = *(const float4*)(src + 4);
        half8v a;
        a[0] = (_Float16)x0.x; a[1] = (_Float16)x0.y;
        a[2] = (_Float16)x0.z; a[3] = (_Float16)x0.w;
        a[4] = (_Float16)x1.x; a[5] = (_Float16)x1.y;
        a[6] = (_Float16)x1.z; a[7] = (_Float16)x1.w;
        af[ks] = a;
    }

    const int orow0 = rb + (l >> 4) * 4;         // C/D: row=(l>>4)*4+reg
#pragma unroll
    for (int c = 0; c < 8; ++c) {                // col-tiles
        f32x4 acc = {0.f, 0.f, 0.f, 0.f};
        const int n = (l & 15) + c * 16;
#pragma unroll
        for (int ks = 0; ks < 4; ++ks) {
            int g  = ks * 4 + (l >> 4);
            int pg = g ^ (n & 7);
            half8v bf = *(const half8v*)(wt + n * 128 + pg * 8);
            acc = __builtin_amdgcn_mfma_f32_16x16x32_f16(af[ks], bf, acc, 0, 0, 0);
        }
        const int ocol = c * 16 + (l & 15);      // C/D: col=l&15
#pragma unroll
        for (int r = 0; r < 4; ++r) {
            int orow = orow0 + r;
            if (orow < N)
                xwh[(size_t)orow * FIN + ocol] = (_Float16)acc[r];
        }
    }
}

// --------------------------------------- pass A: bin edges by bucket --------
__global__ __launch_bounds__(256) void k_bin(
    const int* __restrict__ ei, int* __restrict__ bcur,
    int2* __restrict__ binned, int E, int NB)
{
    __shared__ int hist[MAXNB], scur[MAXNB], gbase[MAXNB], sbase[MAXNB];
    __shared__ int ssum[256];
    __shared__ int2 st[BCH];
    const int tid = threadIdx.x;
    const int e0  = blockIdx.x * BCH;
    const int nE  = min(BCH, E - e0);

    for (int b = tid; b < NB; b += 256) hist[b] = 0;
    __syncthreads();

    for (int k = tid; k < nE; k += 256)
        atomicAdd(&hist[ei[E + e0 + k] >> 8], 1);
    __syncthreads();

    // exclusive scan hist -> sbase (2 elems/thread over padded 512)
    int h0 = (2 * tid     < NB) ? hist[2 * tid]     : 0;
    int h1 = (2 * tid + 1 < NB) ? hist[2 * tid + 1] : 0;
    ssum[tid] = h0 + h1;
    __syncthreads();
    for (int o = 1; o < 256; o <<= 1) {
        int y = (tid >= o) ? ssum[tid - o] : 0;
        __syncthreads();
        ssum[tid] += y;
        __syncthreads();
    }
    int eb = ssum[tid] - h0 - h1;
    if (2 * tid     < NB) { sbase[2 * tid]     = eb;      scur[2 * tid]     = eb; }
    if (2 * tid + 1 < NB) { sbase[2 * tid + 1] = eb + h0; scur[2 * tid + 1] = eb + h0; }
    __syncthreads();

    // claim global per-bucket ranges (one atomic per non-empty bucket)
    for (int b = tid; b < NB; b += 256)
        if (hist[b] > 0) gbase[b] = atomicAdd(bcur + b, hist[b]);

    // LDS reorder by bucket
    for (int k = tid; k < nE; k += 256) {
        int r = ei[e0 + k];
        int c = ei[E + e0 + k];
        int s = atomicAdd(&scur[c >> 8], 1);
        st[s] = make_int2(r, c);
    }
    __syncthreads();

    // coalesced-run flush (bucket recomputed from col)
    for (int s = tid; s < nE; s += 256) {
        int2 rc = st[s];
        int b = rc.y >> 8;
        long dest = (long)b * BCAP + gbase[b] + (s - sbase[b]);
        binned[dest] = rc;
    }
}

// ------------------- parallel scan: bucket totals -> bucket bases -----------
__global__ __launch_bounds__(256) void k_bscan(
    const int* __restrict__ bcur, int* __restrict__ bbase, int NB)
{
    __shared__ int s[256];
    const int t = threadIdx.x;
    int a = (2 * t     < NB) ? bcur[2 * t]     : 0;
    int b = (2 * t + 1 < NB) ? bcur[2 * t + 1] : 0;
    s[t] = a + b;
    __syncthreads();
    for (int o = 1; o < 256; o <<= 1) {
        int y = (t >= o) ? s[t - o] : 0;
        __syncthreads();
        s[t] += y;
        __syncthreads();
    }
    int excl = s[t] - a - b;
    if (2 * t     < NB) bbase[2 * t]     = excl;
    if (2 * t + 1 < NB) bbase[2 * t + 1] = excl + a;
}

// ---------------- pass B: per-bucket degree+scan+place, coalesced write -----
__global__ __launch_bounds__(256) void k_place(
    const int2* __restrict__ binned, const int* __restrict__ bcur,
    const int* __restrict__ bbase, int* __restrict__ cnt, int* __restrict__ off,
    float* __restrict__ dinv, int* __restrict__ sedge, int N)
{
    const int b   = blockIdx.x;
    const int tid = threadIdx.x;
    const int nlo = b << 8;
    const int nn  = min(NPB, N - nlo);
    __shared__ int lcnt[NPB], loff[NPB], lscan[NPB];
    __shared__ int stage[CAPB];
    lcnt[tid] = 0;
    __syncthreads();
    const int ke = bcur[b];
    const int2* src = binned + (long)b * BCAP;
    // pass 1: per-node degree
    for (int k = tid; k < ke; k += 256)
        atomicAdd(&lcnt[src[k].y - nlo], 1);
    __syncthreads();
    // exclusive scan of lcnt[256]
    int v = lcnt[tid];
    lscan[tid] = v;
    __syncthreads();
    for (int o = 1; o < 256; o <<= 1) {
        int y = (tid >= o) ? lscan[tid - o] : 0;
        __syncthreads();
        lscan[tid] += y;
        __syncthreads();
    }
    int excl = lscan[tid] - v;
    loff[tid] = excl;
    const int base = bbase[b];
    if (tid < nn) {
        cnt[nlo + tid]  = v;
        off[nlo + tid]  = base + excl;
        dinv[nlo + tid] = rsqrtf((float)v + 1.0f);
    }
    lcnt[tid] = 0;
    __syncthreads();
    // pass 2: place source ids
    if (ke <= CAPB) {
        for (int k = tid; k < ke; k += 256) {
            int2 rc = src[k];
            int li = rc.y - nlo;
            int p = atomicAdd(&lcnt[li], 1);
            stage[loff[li] + p] = rc.x;
        }
        __syncthreads();
        for (int s = tid; s < ke; s += 256) sedge[base + s] = stage[s];
    } else {   // statistically impossible overflow fallback
        for (int k = tid; k < ke; k += 256) {
            int2 rc = src[k];
            int li = rc.y - nlo;
            int p = atomicAdd(&lcnt[li], 1);
            sedge[base + loff[li] + p] = rc.x;
        }
    }
}

// ------------------------- fused: layer-1 aggregate + relu + layer-2 dots ---
// 4 nodes per wave (one per 16-lane group); lane owns features l16*4..+3.
__global__ __launch_bounds__(256) void k_fused(
    const int* __restrict__ off, const int* __restrict__ cnt,
    const int* __restrict__ sedge, const float* __restrict__ dinv,
    const _Float16* __restrict__ xwh,
    const float* __restrict__ b1, const float* __restrict__ bf1,
    const float* __restrict__ W2, const float* __restrict__ Wf2,
    const float* __restrict__ b2, const float* __restrict__ bf2,
    float* __restrict__ z, float* __restrict__ out, int N)
{
    const int wv   = (blockIdx.x * blockDim.x + threadIdx.x) >> 6;  // wave id
    const int lane = threadIdx.x & 63;
    const int g    = lane >> 4;        // node slot 0..3
    const int l16  = lane & 15;        // feature quad: features l16*4..+3
    int i = wv * 4 + g;
    const bool ok = (i < N);
    i = ok ? i : (N - 1);

    const int jb  = off[i];
    const int deg = cnt[i];
    const float di = dinv[i];

    float4 acc = make_float4(0.f, 0.f, 0.f, 0.f);
    int j = 0;
    for (; j + 4 <= deg; j += 4) {   // 4 gathers in flight per group
        int r0 = sedge[jb + j];
        int r1 = sedge[jb + j + 1];
        int r2 = sedge[jb + j + 2];
        int r3 = sedge[jb + j + 3];
        float s0 = dinv[r0] * di;
        float s1 = dinv[r1] * di;
        float s2 = dinv[r2] * di;
        float s3 = dinv[r3] * di;
        half4v a0 = *(const half4v*)(xwh + (size_t)r0 * FIN + l16 * 4);
        half4v a1 = *(const half4v*)(xwh + (size_t)r1 * FIN + l16 * 4);
        half4v a2 = *(const half4v*)(xwh + (size_t)r2 * FIN + l16 * 4);
        half4v a3 = *(const half4v*)(xwh + (size_t)r3 * FIN + l16 * 4);
        acc.x = fmaf((float)a0[0], s0, acc.x);
        acc.y = fmaf((float)a0[1], s0, acc.y);
        acc.z = fmaf((float)a0[2], s0, acc.z);
        acc.w = fmaf((float)a0[3], s0, acc.w);
        acc.x = fmaf((float)a1[0], s1, acc.x);
        acc.y = fmaf((float)a1[1], s1, acc.y);
        acc.z = fmaf((float)a1[2], s1, acc.z);
        acc.w = fmaf((float)a1[3], s1, acc.w);
        acc.x = fmaf((float)a2[0], s2, acc.x);
        acc.y = fmaf((float)a2[1], s2, acc.y);
        acc.z = fmaf((float)a2[2], s2, acc.z);
        acc.w = fmaf((float)a2[3], s2, acc.w);
        acc.x = fmaf((float)a3[0], s3, acc.x);
        acc.y = fmaf((float)a3[1], s3, acc.y);
        acc.z = fmaf((float)a3[2], s3, acc.z);
        acc.w = fmaf((float)a3[3], s3, acc.w);
    }
    for (; j < deg; ++j) {
        int r = sedge[jb + j];
        float s = dinv[r] * di;
        half4v a = *(const half4v*)(xwh + (size_t)r * FIN + l16 * 4);
        acc.x = fmaf((float)a[0], s, acc.x);
        acc.y = fmaf((float)a[1], s, acc.y);
        acc.z = fmaf((float)a[2], s, acc.z);
        acc.w = fmaf((float)a[3], s, acc.w);
    }

    // self loop (fp16 row)
    float dd = di * di;
    half4v svh = *(const half4v*)(xwh + (size_t)i * FIN + l16 * 4);
    acc.x = fmaf((float)svh[0], dd, acc.x);
    acc.y = fmaf((float)svh[1], dd, acc.y);
    acc.z = fmaf((float)svh[2], dd, acc.z);
    acc.w = fmaf((float)svh[3], dd, acc.w);

    // epilogue: relu + two 128-dots (weights l16-indexed: shared by 4 nodes)
    float4 b1v  = *(const float4*)(b1  + l16 * 4);
    float4 bf1v = *(const float4*)(bf1 + l16 * 4);
    half4v x1h  = *(const half4v*)(xwh + (size_t)i * FIN + HH + l16 * 4);
    float4 h0, h1;
    h0.x = fmaxf(acc.x + b1v.x, 0.f);  h0.y = fmaxf(acc.y + b1v.y, 0.f);
    h0.z = fmaxf(acc.z + b1v.z, 0.f);  h0.w = fmaxf(acc.w + b1v.w, 0.f);
    h1.x = fmaxf((float)x1h[0] + bf1v.x, 0.f);  h1.y = fmaxf((float)x1h[1] + bf1v.y, 0.f);
    h1.z = fmaxf((float)x1h[2] + bf1v.z, 0.f);  h1.w = fmaxf((float)x1h[3] + bf1v.w, 0.f);

    float4 w2a  = *(const float4*)(W2  + l16 * 4);
    float4 w2b  = *(const float4*)(W2  + HH + l16 * 4);
    float4 wf2a = *(const float4*)(Wf2 + l16 * 4);
    float4 wf2b = *(const float4*)(Wf2 + HH + l16 * 4);

    float zp = h0.x * w2a.x + h0.y * w2a.y + h0.z * w2a.z + h0.w * w2a.w
             + h1.x * w2b.x + h1.y * w2b.y + h1.z * w2b.z + h1.w * w2b.w;
    float fp = h0.x * wf2a.x + h0.y * wf2a.y + h0.z * wf2a.z + h0.w * wf2a.w
             + h1.x * wf2b.x + h1.y * wf2b.y + h1.z * wf2b.z + h1.w * wf2b.w;
#pragma unroll
    for (int o = 8; o > 0; o >>= 1) {
        zp += __shfl_xor(zp, o, 16);   // reduce within the 16-lane group
        fp += __shfl_xor(fp, o, 16);
    }
    if (l16 == 0 && ok) {
        z[i]   = zp;
        out[i] = fp + b2[0] + bf2[0];
    }
}

// ------------------------------------------- layer-2 aggregate (CSR) --------
// out[i] += di * ( sum_j z[r_j]*dinv[r_j]  +  z[i]*di )
__global__ __launch_bounds__(256) void k_agg2(
    const int* __restrict__ off, const int* __restrict__ cnt,
    const int* __restrict__ sedge, const float* __restrict__ dinv,
    const float* __restrict__ z, float* __restrict__ out, int N)
{
    const int wid  = (blockIdx.x * blockDim.x + threadIdx.x) >> 6;
    const int lane = threadIdx.x & 63;
    const int g    = lane >> 4;
    const int l16  = lane & 15;
    int i = wid * 4 + g;
    bool ok = (i < N);
    i = ok ? i : (N - 1);

    const int jb = off[i], je = jb + cnt[i];
    float s = 0.0f;
    for (int j = jb + l16; j < je; j += 16) {
        int r = sedge[j];
        s = fmaf(z[r], dinv[r], s);
    }
#pragma unroll
    for (int o = 8; o > 0; o >>= 1) s += __shfl_xor(s, o, 64);
    if (l16 == 0 && ok) {
        float di = dinv[i];
        out[i] += di * fmaf(z[i], di, s);
    }
}

// ---------------------------------------------------------------- launch ----
extern "C" void kernel_launch(void* const* d_in, const int* in_sizes, int n_in,
                              void* d_out, int out_size, void* d_ws, size_t ws_size,
                              hipStream_t stream)
{
    const float* x   = (const float*)d_in[0];
    const int*   ei  = (const int*)d_in[1];    // [2,E]: row=ei[e], col=ei[E+e]
    const float* W1  = (const float*)d_in[2];
    const float* b1  = (const float*)d_in[3];
    const float* Wf1 = (const float*)d_in[4];
    const float* bf1 = (const float*)d_in[5];
    const float* W2  = (const float*)d_in[6];
    const float* b2  = (const float*)d_in[7];
    const float* Wf2 = (const float*)d_in[8];
    const float* bf2 = (const float*)d_in[9];

    const int N = in_sizes[0] / FIN;   // 100000
    const int E = in_sizes[1] / 2;     // 1600000
    const int NB = (N + NPB - 1) / NPB;  // 391 buckets
    float* out = (float*)d_out;

    // workspace layout (4-byte units):
    // dinv[N] | z[N] | cnt[N] | bcur[MAXNB] | bbase[MAXNB] | off[N] |
    // sedge int[E] | xwh[N*128 halves] | binned[NB*BCAP int2]
    float* ws   = (float*)d_ws;
    float* dinv = ws;
    float* z    = dinv + N;
    int*   cnt  = (int*)(z + N);
    int*   bcur = cnt + N;
    int*   bbase = bcur + MAXNB;
    int*   off  = bbase + MAXNB;
    int*   sedge = off + N;
    _Float16* xwh = (_Float16*)(sedge + E);
    int2*  binned = (int2*)(xwh + (size_t)N * FIN);

    hipMemsetAsync(bcur, 0, (size_t)MAXNB * sizeof(int), stream);

    k_bin<<<(E + BCH - 1) / BCH, 256, 0, stream>>>(ei, bcur, binned, E, NB);
    k_bscan<<<1, 256, 0, stream>>>(bcur, bbase, NB);
    k_place<<<NB, 256, 0, stream>>>(binned, bcur, bbase, cnt, off, dinv, sedge, N);

    k_gemm<<<(N + 63) / 64, 256, 0, stream>>>(x, W1, Wf1, xwh, N);

    {
        long waves = ((long)N + 3) / 4;        // one wave per 4 nodes
        int blocks = (int)((waves * 64 + 255) / 256);
        k_fused<<<blocks, 256, 0, stream>>>(off, cnt, sedge, dinv, xwh,
                                            b1, bf1, W2, Wf2, b2, bf2, z, out, N);
    }

    {
        long waves = ((long)N + 3) / 4;        // one wave per 4 nodes
        int blocks = (int)((waves * 64 + 255) / 256);
        k_agg2<<<blocks, 256, 0, stream>>>(off, cnt, sedge, dinv, z, out, N);
    }
}

// Round 20
// 212.778 us; speedup vs baseline: 1.1894x; 1.0006x over previous
//
#include <hip/hip_runtime.h>
#include <hip/hip_fp16.h>

constexpr int FIN   = 128;   // input features (also total hidden width)
constexpr int HH    = 64;    // half hidden (GCN branch width)
constexpr int NPB   = 256;   // nodes per bucket (bucket = col >> 8)
constexpr int MAXNB = 512;   // max buckets supported (N <= 131072)
constexpr int BCH   = 4096;  // edges per k_bin block
constexpr int BCAP  = 4608;  // bucket stride in binned[]
constexpr int CAPB  = 4500;  // LDS stage capacity in k_place

typedef _Float16 half4v __attribute__((ext_vector_type(4)));
typedef _Float16 half8v __attribute__((ext_vector_type(8)));
typedef float    f32x4 __attribute__((ext_vector_type(4)));

// ------------------------------------------------------------------ GEMM ----
// MFMA: xwh[N,128] = fp16( x @ [W1|Wf1] ), fp32 accumulate.
__global__ __launch_bounds__(256) void k_gemm(
    const float* __restrict__ x, const float* __restrict__ W1,
    const float* __restrict__ Wf1, _Float16* __restrict__ xwh, int N)
{
    __shared__ _Float16 wt[128 * 128];   // wt[n][k] swizzled, 32KB

    const int tid = threadIdx.x;
    // stage W^T fp16 (coalesced fp32 reads: consecutive tid -> consecutive n)
    for (int idx = tid; idx < 128 * 128; idx += 256) {
        int n = idx & 127, k = idx >> 7;
        float v = (n < HH) ? W1[k * HH + n] : Wf1[k * HH + (n - HH)];
        int g  = k >> 3, j = k & 7;
        int pg = g ^ (n & 7);                    // bank swizzle
        wt[n * 128 + pg * 8 + j] = (_Float16)v;
    }
    __syncthreads();

    const int w  = tid >> 6;                     // wave 0..3
    const int l  = tid & 63;
    const int rb = blockIdx.x * 64 + w * 16;     // this wave's 16 rows

    // A fragments: row = l&15, k = ks*32 + (l>>4)*8 + j  (global fp32 -> fp16)
    int arow = rb + (l & 15);
    arow = (arow < N) ? arow : (N - 1);
    half8v af[4];
#pragma unroll
    for (int ks = 0; ks < 4; ++ks) {
        const float* src = x + (size_t)arow * FIN + ks * 32 + (l >> 4) * 8;
        float4 x0 = *(const float4*)(src);
        float4 x1 = *(const float4*)(src + 4);
        half8v a;
        a[0] = (_Float16)x0.x; a[1] = (_Float16)x0.y;
        a[2] = (_Float16)x0.z; a[3] = (_Float16)x0.w;
        a[4] = (_Float16)x1.x; a[5] = (_Float16)x1.y;
        a[6] = (_Float16)x1.z; a[7] = (_Float16)x1.w;
        af[ks] = a;
    }

    const int orow0 = rb + (l >> 4) * 4;         // C/D: row=(l>>4)*4+reg
#pragma unroll
    for (int c = 0; c < 8; ++c) {                // col-tiles
        f32x4 acc = {0.f, 0.f, 0.f, 0.f};
        const int n = (l & 15) + c * 16;
#pragma unroll
        for (int ks = 0; ks < 4; ++ks) {
            int g  = ks * 4 + (l >> 4);
            int pg = g ^ (n & 7);
            half8v bf = *(const half8v*)(wt + n * 128 + pg * 8);
            acc = __builtin_amdgcn_mfma_f32_16x16x32_f16(af[ks], bf, acc, 0, 0, 0);
        }
        const int ocol = c * 16 + (l & 15);      // C/D: col=l&15
#pragma unroll
        for (int r = 0; r < 4; ++r) {
            int orow = orow0 + r;
            if (orow < N)
                xwh[(size_t)orow * FIN + ocol] = (_Float16)acc[r];
        }
    }
}

// --------------------------------------- pass A: bin edges by bucket --------
// binned entry packed: (li<<24)|r  where li = c&255, r < 2^24. Halves the
// binned stream bytes (k_bin WRITE, k_place FETCH) vs int2.
__global__ __launch_bounds__(256) void k_bin(
    const int* __restrict__ ei, int* __restrict__ bcur,
    int* __restrict__ binned, int E, int NB)
{
    __shared__ int hist[MAXNB], scur[MAXNB], gbase[MAXNB], sbase[MAXNB];
    __shared__ int ssum[256];
    __shared__ int2 st[BCH];
    const int tid = threadIdx.x;
    const int e0  = blockIdx.x * BCH;
    const int nE  = min(BCH, E - e0);

    for (int b = tid; b < NB; b += 256) hist[b] = 0;
    __syncthreads();

    for (int k = tid; k < nE; k += 256)
        atomicAdd(&hist[ei[E + e0 + k] >> 8], 1);
    __syncthreads();

    // exclusive scan hist -> sbase (2 elems/thread over padded 512)
    int h0 = (2 * tid     < NB) ? hist[2 * tid]     : 0;
    int h1 = (2 * tid + 1 < NB) ? hist[2 * tid + 1] : 0;
    ssum[tid] = h0 + h1;
    __syncthreads();
    for (int o = 1; o < 256; o <<= 1) {
        int y = (tid >= o) ? ssum[tid - o] : 0;
        __syncthreads();
        ssum[tid] += y;
        __syncthreads();
    }
    int eb = ssum[tid] - h0 - h1;
    if (2 * tid     < NB) { sbase[2 * tid]     = eb;      scur[2 * tid]     = eb; }
    if (2 * tid + 1 < NB) { sbase[2 * tid + 1] = eb + h0; scur[2 * tid + 1] = eb + h0; }
    __syncthreads();

    // claim global per-bucket ranges (one atomic per non-empty bucket)
    for (int b = tid; b < NB; b += 256)
        if (hist[b] > 0) gbase[b] = atomicAdd(bcur + b, hist[b]);

    // LDS reorder by bucket
    for (int k = tid; k < nE; k += 256) {
        int r = ei[e0 + k];
        int c = ei[E + e0 + k];
        int s = atomicAdd(&scur[c >> 8], 1);
        st[s] = make_int2(r, c);
    }
    __syncthreads();

    // coalesced-run flush (bucket recomputed from col; entry packed)
    for (int s = tid; s < nE; s += 256) {
        int2 rc = st[s];
        int b = rc.y >> 8;
        long dest = (long)b * BCAP + gbase[b] + (s - sbase[b]);
        binned[dest] = ((rc.y & 255) << 24) | rc.x;
    }
}

// ------------------- parallel scan: bucket totals -> bucket bases -----------
__global__ __launch_bounds__(256) void k_bscan(
    const int* __restrict__ bcur, int* __restrict__ bbase, int NB)
{
    __shared__ int s[256];
    const int t = threadIdx.x;
    int a = (2 * t     < NB) ? bcur[2 * t]     : 0;
    int b = (2 * t + 1 < NB) ? bcur[2 * t + 1] : 0;
    s[t] = a + b;
    __syncthreads();
    for (int o = 1; o < 256; o <<= 1) {
        int y = (t >= o) ? s[t - o] : 0;
        __syncthreads();
        s[t] += y;
        __syncthreads();
    }
    int excl = s[t] - a - b;
    if (2 * t     < NB) bbase[2 * t]     = excl;
    if (2 * t + 1 < NB) bbase[2 * t + 1] = excl + a;
}

// ---------------- pass B: per-bucket degree+scan+place, coalesced write -----
__global__ __launch_bounds__(256) void k_place(
    const int* __restrict__ binned, const int* __restrict__ bcur,
    const int* __restrict__ bbase, int* __restrict__ cnt, int* __restrict__ off,
    float* __restrict__ dinv, int* __restrict__ sedge, int N)
{
    const int b   = blockIdx.x;
    const int tid = threadIdx.x;
    const int nlo = b << 8;
    const int nn  = min(NPB, N - nlo);
    __shared__ int lcnt[NPB], loff[NPB], lscan[NPB];
    __shared__ int stage[CAPB];
    lcnt[tid] = 0;
    __syncthreads();
    const int ke = bcur[b];
    const int* src = binned + (long)b * BCAP;
    // pass 1: per-node degree (li = packed>>24)
    for (int k = tid; k < ke; k += 256)
        atomicAdd(&lcnt[((unsigned)src[k]) >> 24], 1);
    __syncthreads();
    // exclusive scan of lcnt[256]
    int v = lcnt[tid];
    lscan[tid] = v;
    __syncthreads();
    for (int o = 1; o < 256; o <<= 1) {
        int y = (tid >= o) ? lscan[tid - o] : 0;
        __syncthreads();
        lscan[tid] += y;
        __syncthreads();
    }
    int excl = lscan[tid] - v;
    loff[tid] = excl;
    const int base = bbase[b];
    if (tid < nn) {
        cnt[nlo + tid]  = v;
        off[nlo + tid]  = base + excl;
        dinv[nlo + tid] = rsqrtf((float)v + 1.0f);
    }
    lcnt[tid] = 0;
    __syncthreads();
    // pass 2: place source ids
    if (ke <= CAPB) {
        for (int k = tid; k < ke; k += 256) {
            int p  = src[k];
            int li = ((unsigned)p) >> 24;
            int q  = atomicAdd(&lcnt[li], 1);
            stage[loff[li] + q] = p & 0x00FFFFFF;
        }
        __syncthreads();
        for (int s = tid; s < ke; s += 256) sedge[base + s] = stage[s];
    } else {   // statistically impossible overflow fallback
        for (int k = tid; k < ke; k += 256) {
            int p  = src[k];
            int li = ((unsigned)p) >> 24;
            int q  = atomicAdd(&lcnt[li], 1);
            sedge[base + loff[li] + q] = p & 0x00FFFFFF;
        }
    }
}

// ------------------------- fused: layer-1 aggregate + relu + layer-2 dots ---
// 4 nodes per wave (one per 16-lane group); lane owns features l16*4..+3.
__global__ __launch_bounds__(256) void k_fused(
    const int* __restrict__ off, const int* __restrict__ cnt,
    const int* __restrict__ sedge, const float* __restrict__ dinv,
    const _Float16* __restrict__ xwh,
    const float* __restrict__ b1, const float* __restrict__ bf1,
    const float* __restrict__ W2, const float* __restrict__ Wf2,
    const float* __restrict__ b2, const float* __restrict__ bf2,
    float* __restrict__ z, float* __restrict__ out, int N)
{
    const int wv   = (blockIdx.x * blockDim.x + threadIdx.x) >> 6;  // wave id
    const int lane = threadIdx.x & 63;
    const int g    = lane >> 4;        // node slot 0..3
    const int l16  = lane & 15;        // feature quad: features l16*4..+3
    int i = wv * 4 + g;
    const bool ok = (i < N);
    i = ok ? i : (N - 1);

    const int jb  = off[i];
    const int deg = cnt[i];
    const float di = dinv[i];

    float4 acc = make_float4(0.f, 0.f, 0.f, 0.f);
    int j = 0;
    for (; j + 4 <= deg; j += 4) {   // 4 gathers in flight per group
        int r0 = sedge[jb + j];
        int r1 = sedge[jb + j + 1];
        int r2 = sedge[jb + j + 2];
        int r3 = sedge[jb + j + 3];
        float s0 = dinv[r0] * di;
        float s1 = dinv[r1] * di;
        float s2 = dinv[r2] * di;
        float s3 = dinv[r3] * di;
        half4v a0 = *(const half4v*)(xwh + (size_t)r0 * FIN + l16 * 4);
        half4v a1 = *(const half4v*)(xwh + (size_t)r1 * FIN + l16 * 4);
        half4v a2 = *(const half4v*)(xwh + (size_t)r2 * FIN + l16 * 4);
        half4v a3 = *(const half4v*)(xwh + (size_t)r3 * FIN + l16 * 4);
        acc.x = fmaf((float)a0[0], s0, acc.x);
        acc.y = fmaf((float)a0[1], s0, acc.y);
        acc.z = fmaf((float)a0[2], s0, acc.z);
        acc.w = fmaf((float)a0[3], s0, acc.w);
        acc.x = fmaf((float)a1[0], s1, acc.x);
        acc.y = fmaf((float)a1[1], s1, acc.y);
        acc.z = fmaf((float)a1[2], s1, acc.z);
        acc.w = fmaf((float)a1[3], s1, acc.w);
        acc.x = fmaf((float)a2[0], s2, acc.x);
        acc.y = fmaf((float)a2[1], s2, acc.y);
        acc.z = fmaf((float)a2[2], s2, acc.z);
        acc.w = fmaf((float)a2[3], s2, acc.w);
        acc.x = fmaf((float)a3[0], s3, acc.x);
        acc.y = fmaf((float)a3[1], s3, acc.y);
        acc.z = fmaf((float)a3[2], s3, acc.z);
        acc.w = fmaf((float)a3[3], s3, acc.w);
    }
    for (; j < deg; ++j) {
        int r = sedge[jb + j];
        float s = dinv[r] * di;
        half4v a = *(const half4v*)(xwh + (size_t)r * FIN + l16 * 4);
        acc.x = fmaf((float)a[0], s, acc.x);
        acc.y = fmaf((float)a[1], s, acc.y);
        acc.z = fmaf((float)a[2], s, acc.z);
        acc.w = fmaf((float)a[3], s, acc.w);
    }

    // self loop (fp16 row)
    float dd = di * di;
    half4v svh = *(const half4v*)(xwh + (size_t)i * FIN + l16 * 4);
    acc.x = fmaf((float)svh[0], dd, acc.x);
    acc.y = fmaf((float)svh[1], dd, acc.y);
    acc.z = fmaf((float)svh[2], dd, acc.z);
    acc.w = fmaf((float)svh[3], dd, acc.w);

    // epilogue: relu + two 128-dots (weights l16-indexed: shared by 4 nodes)
    float4 b1v  = *(const float4*)(b1  + l16 * 4);
    float4 bf1v = *(const float4*)(bf1 + l16 * 4);
    half4v x1h  = *(const half4v*)(xwh + (size_t)i * FIN + HH + l16 * 4);
    float4 h0, h1;
    h0.x = fmaxf(acc.x + b1v.x, 0.f);  h0.y = fmaxf(acc.y + b1v.y, 0.f);
    h0.z = fmaxf(acc.z + b1v.z, 0.f);  h0.w = fmaxf(acc.w + b1v.w, 0.f);
    h1.x = fmaxf((float)x1h[0] + bf1v.x, 0.f);  h1.y = fmaxf((float)x1h[1] + bf1v.y, 0.f);
    h1.z = fmaxf((float)x1h[2] + bf1v.z, 0.f);  h1.w = fmaxf((float)x1h[3] + bf1v.w, 0.f);

    float4 w2a  = *(const float4*)(W2  + l16 * 4);
    float4 w2b  = *(const float4*)(W2  + HH + l16 * 4);
    float4 wf2a = *(const float4*)(Wf2 + l16 * 4);
    float4 wf2b = *(const float4*)(Wf2 + HH + l16 * 4);

    float zp = h0.x * w2a.x + h0.y * w2a.y + h0.z * w2a.z + h0.w * w2a.w
             + h1.x * w2b.x + h1.y * w2b.y + h1.z * w2b.z + h1.w * w2b.w;
    float fp = h0.x * wf2a.x + h0.y * wf2a.y + h0.z * wf2a.z + h0.w * wf2a.w
             + h1.x * wf2b.x + h1.y * wf2b.y + h1.z * wf2b.z + h1.w * wf2b.w;
#pragma unroll
    for (int o = 8; o > 0; o >>= 1) {
        zp += __shfl_xor(zp, o, 16);   // reduce within the 16-lane group
        fp += __shfl_xor(fp, o, 16);
    }
    if (l16 == 0 && ok) {
        z[i]   = zp;
        out[i] = fp + b2[0] + bf2[0];
    }
}

// ------------------------------------------- layer-2 aggregate (CSR) --------
// out[i] += di * ( sum_j z[r_j]*dinv[r_j]  +  z[i]*di )
__global__ __launch_bounds__(256) void k_agg2(
    const int* __restrict__ off, const int* __restrict__ cnt,
    const int* __restrict__ sedge, const float* __restrict__ dinv,
    const float* __restrict__ z, float* __restrict__ out, int N)
{
    const int wid  = (blockIdx.x * blockDim.x + threadIdx.x) >> 6;
    const int lane = threadIdx.x & 63;
    const int g    = lane >> 4;
    const int l16  = lane & 15;
    int i = wid * 4 + g;
    bool ok = (i < N);
    i = ok ? i : (N - 1);

    const int jb = off[i], je = jb + cnt[i];
    float s = 0.0f;
    for (int j = jb + l16; j < je; j += 16) {
        int r = sedge[j];
        s = fmaf(z[r], dinv[r], s);
    }
#pragma unroll
    for (int o = 8; o > 0; o >>= 1) s += __shfl_xor(s, o, 64);
    if (l16 == 0 && ok) {
        float di = dinv[i];
        out[i] += di * fmaf(z[i], di, s);
    }
}

// ---------------------------------------------------------------- launch ----
extern "C" void kernel_launch(void* const* d_in, const int* in_sizes, int n_in,
                              void* d_out, int out_size, void* d_ws, size_t ws_size,
                              hipStream_t stream)
{
    const float* x   = (const float*)d_in[0];
    const int*   ei  = (const int*)d_in[1];    // [2,E]: row=ei[e], col=ei[E+e]
    const float* W1  = (const float*)d_in[2];
    const float* b1  = (const float*)d_in[3];
    const float* Wf1 = (const float*)d_in[4];
    const float* bf1 = (const float*)d_in[5];
    const float* W2  = (const float*)d_in[6];
    const float* b2  = (const float*)d_in[7];
    const float* Wf2 = (const float*)d_in[8];
    const float* bf2 = (const float*)d_in[9];

    const int N = in_sizes[0] / FIN;   // 100000
    const int E = in_sizes[1] / 2;     // 1600000
    const int NB = (N + NPB - 1) / NPB;  // 391 buckets
    float* out = (float*)d_out;

    // workspace layout (4-byte units):
    // dinv[N] | z[N] | cnt[N] | bcur[MAXNB] | bbase[MAXNB] | off[N] |
    // sedge int[E] | xwh[N*128 halves] | binned int[NB*BCAP]
    float* ws   = (float*)d_ws;
    float* dinv = ws;
    float* z    = dinv + N;
    int*   cnt  = (int*)(z + N);
    int*   bcur = cnt + N;
    int*   bbase = bcur + MAXNB;
    int*   off  = bbase + MAXNB;
    int*   sedge = off + N;
    _Float16* xwh = (_Float16*)(sedge + E);
    int*   binned = (int*)(xwh + (size_t)N * FIN);

    hipMemsetAsync(bcur, 0, (size_t)MAXNB * sizeof(int), stream);

    k_bin<<<(E + BCH - 1) / BCH, 256, 0, stream>>>(ei, bcur, binned, E, NB);
    k_bscan<<<1, 256, 0, stream>>>(bcur, bbase, NB);
    k_place<<<NB, 256, 0, stream>>>(binned, bcur, bbase, cnt, off, dinv, sedge, N);

    k_gemm<<<(N + 63) / 64, 256, 0, stream>>>(x, W1, Wf1, xwh, N);

    {
        long waves = ((long)N + 3) / 4;        // one wave per 4 nodes
        int blocks = (int)((waves * 64 + 255) / 256);
        k_fused<<<blocks, 256, 0, stream>>>(off, cnt, sedge, dinv, xwh,
                                            b1, bf1, W2, Wf2, b2, bf2, z, out, N);
    }

    {
        long waves = ((long)N + 3) / 4;        // one wave per 4 nodes
        int blocks = (int)((waves * 64 + 255) / 256);
        k_agg2<<<blocks, 256, 0, stream>>>(off, cnt, sedge, dinv, z, out, N);
    }
}

// Round 21
// 206.499 us; speedup vs baseline: 1.2255x; 1.0304x over previous
//
#include <hip/hip_runtime.h>
#include <hip/hip_fp16.h>

constexpr int FIN   = 128;   // input features (also total hidden width)
constexpr int HH    = 64;    // half hidden (GCN branch width)
constexpr int NPB   = 256;   // nodes per bucket (bucket = col >> 8)
constexpr int MAXNB = 512;   // max buckets supported (N <= 131072)
constexpr int BCH   = 4096;  // edges per bin block
constexpr int BCAP  = 4608;  // bucket stride in binned[]
constexpr int CAPB  = 4500;  // LDS stage capacity in k_place

// merged bin+gemm shared memory: st[BCH] int2 (32KB) | hist/scur/gbase/sbase
// (4*512 ints = 8KB) | ssum (1KB)  => 41984 B.  gemm role reuses the first
// 32KB as the fp16 W^T tile.
constexpr int SMEM_BYTES = BCH * 8 + 4 * MAXNB * 4 + 256 * 4;

typedef _Float16 half4v __attribute__((ext_vector_type(4)));
typedef _Float16 half8v __attribute__((ext_vector_type(8)));
typedef float    f32x4 __attribute__((ext_vector_type(4)));

// ------------------- merged: CSR bin (blocks < nbin) + MFMA GEMM (rest) -----
// k_bin and k_gemm have no data dependency (ei vs x/W). Serially they ran
// ~35-40us (latency-bound, 1.5 blk/CU) + ~20-25us (streaming). One dual-role
// dispatch lets gemm waves fill the bin blocks' latency stalls.
__global__ __launch_bounds__(256) void k_bingemm(
    const int* __restrict__ ei, int* __restrict__ bcur,
    int* __restrict__ binned, int E, int NB, int nbin,
    const float* __restrict__ x, const float* __restrict__ W1,
    const float* __restrict__ Wf1, _Float16* __restrict__ xwh, int N)
{
    __shared__ __align__(16) char smem[SMEM_BYTES];
    const int tid = threadIdx.x;

    if (blockIdx.x < nbin) {
        // ---------------- bin role: bucket-sort edge chunk into binned[] ----
        int2* st   = (int2*)smem;
        int* hist  = (int*)(smem + BCH * 8);
        int* scur  = hist + MAXNB;
        int* gbase = scur + MAXNB;
        int* sbase = gbase + MAXNB;
        int* ssum  = sbase + MAXNB;

        const int e0 = blockIdx.x * BCH;
        const int nE = min(BCH, E - e0);

        for (int b = tid; b < NB; b += 256) hist[b] = 0;
        __syncthreads();

        for (int k = tid; k < nE; k += 256)
            atomicAdd(&hist[ei[E + e0 + k] >> 8], 1);
        __syncthreads();

        // exclusive scan hist -> sbase (2 elems/thread over padded 512)
        int h0 = (2 * tid     < NB) ? hist[2 * tid]     : 0;
        int h1 = (2 * tid + 1 < NB) ? hist[2 * tid + 1] : 0;
        ssum[tid] = h0 + h1;
        __syncthreads();
        for (int o = 1; o < 256; o <<= 1) {
            int y = (tid >= o) ? ssum[tid - o] : 0;
            __syncthreads();
            ssum[tid] += y;
            __syncthreads();
        }
        int eb = ssum[tid] - h0 - h1;
        if (2 * tid     < NB) { sbase[2 * tid]     = eb;      scur[2 * tid]     = eb; }
        if (2 * tid + 1 < NB) { sbase[2 * tid + 1] = eb + h0; scur[2 * tid + 1] = eb + h0; }
        __syncthreads();

        // claim global per-bucket ranges (one atomic per non-empty bucket)
        for (int b = tid; b < NB; b += 256)
            if (hist[b] > 0) gbase[b] = atomicAdd(bcur + b, hist[b]);

        // LDS reorder by bucket
        for (int k = tid; k < nE; k += 256) {
            int r = ei[e0 + k];
            int c = ei[E + e0 + k];
            int s = atomicAdd(&scur[c >> 8], 1);
            st[s] = make_int2(r, c);
        }
        __syncthreads();

        // coalesced-run flush (entry packed: (li<<24)|r)
        for (int s = tid; s < nE; s += 256) {
            int2 rc = st[s];
            int b = rc.y >> 8;
            long dest = (long)b * BCAP + gbase[b] + (s - sbase[b]);
            binned[dest] = ((rc.y & 255) << 24) | rc.x;
        }
    } else {
        // ---------------- gemm role: xwh[N,128] = fp16(x @ [W1|Wf1]) --------
        _Float16* wt = (_Float16*)smem;      // wt[n][k] swizzled, 32KB

        for (int idx = tid; idx < 128 * 128; idx += 256) {
            int n = idx & 127, k = idx >> 7;
            float v = (n < HH) ? W1[k * HH + n] : Wf1[k * HH + (n - HH)];
            int g  = k >> 3, j = k & 7;
            int pg = g ^ (n & 7);            // bank swizzle
            wt[n * 128 + pg * 8 + j] = (_Float16)v;
        }
        __syncthreads();

        const int w  = tid >> 6;             // wave 0..3
        const int l  = tid & 63;
        const int rb = (blockIdx.x - nbin) * 64 + w * 16;

        int arow = rb + (l & 15);
        arow = (arow < N) ? arow : (N - 1);
        half8v af[4];
#pragma unroll
        for (int ks = 0; ks < 4; ++ks) {
            const float* src = x + (size_t)arow * FIN + ks * 32 + (l >> 4) * 8;
            float4 x0 = *(const float4*)(src);
            float4 x1 = *(const float4*)(src + 4);
            half8v a;
            a[0] = (_Float16)x0.x; a[1] = (_Float16)x0.y;
            a[2] = (_Float16)x0.z; a[3] = (_Float16)x0.w;
            a[4] = (_Float16)x1.x; a[5] = (_Float16)x1.y;
            a[6] = (_Float16)x1.z; a[7] = (_Float16)x1.w;
            af[ks] = a;
        }

        const int orow0 = rb + (l >> 4) * 4;
#pragma unroll
        for (int c = 0; c < 8; ++c) {
            f32x4 acc = {0.f, 0.f, 0.f, 0.f};
            const int n = (l & 15) + c * 16;
#pragma unroll
            for (int ks = 0; ks < 4; ++ks) {
                int g  = ks * 4 + (l >> 4);
                int pg = g ^ (n & 7);
                half8v bf = *(const half8v*)(wt + n * 128 + pg * 8);
                acc = __builtin_amdgcn_mfma_f32_16x16x32_f16(af[ks], bf, acc, 0, 0, 0);
            }
            const int ocol = c * 16 + (l & 15);
#pragma unroll
            for (int r = 0; r < 4; ++r) {
                int orow = orow0 + r;
                if (orow < N)
                    xwh[(size_t)orow * FIN + ocol] = (_Float16)acc[r];
            }
        }
    }
}

// ------------------- parallel scan: bucket totals -> bucket bases -----------
__global__ __launch_bounds__(256) void k_bscan(
    const int* __restrict__ bcur, int* __restrict__ bbase, int NB)
{
    __shared__ int s[256];
    const int t = threadIdx.x;
    int a = (2 * t     < NB) ? bcur[2 * t]     : 0;
    int b = (2 * t + 1 < NB) ? bcur[2 * t + 1] : 0;
    s[t] = a + b;
    __syncthreads();
    for (int o = 1; o < 256; o <<= 1) {
        int y = (t >= o) ? s[t - o] : 0;
        __syncthreads();
        s[t] += y;
        __syncthreads();
    }
    int excl = s[t] - a - b;
    if (2 * t     < NB) bbase[2 * t]     = excl;
    if (2 * t + 1 < NB) bbase[2 * t + 1] = excl + a;
}

// ---------------- pass B: per-bucket degree+scan+place, coalesced write -----
__global__ __launch_bounds__(256) void k_place(
    const int* __restrict__ binned, const int* __restrict__ bcur,
    const int* __restrict__ bbase, int* __restrict__ cnt, int* __restrict__ off,
    float* __restrict__ dinv, int* __restrict__ sedge, int N)
{
    const int b   = blockIdx.x;
    const int tid = threadIdx.x;
    const int nlo = b << 8;
    const int nn  = min(NPB, N - nlo);
    __shared__ int lcnt[NPB], loff[NPB], lscan[NPB];
    __shared__ int stage[CAPB];
    lcnt[tid] = 0;
    __syncthreads();
    const int ke = bcur[b];
    const int* src = binned + (long)b * BCAP;
    // pass 1: per-node degree (li = packed>>24)
    for (int k = tid; k < ke; k += 256)
        atomicAdd(&lcnt[((unsigned)src[k]) >> 24], 1);
    __syncthreads();
    // exclusive scan of lcnt[256]
    int v = lcnt[tid];
    lscan[tid] = v;
    __syncthreads();
    for (int o = 1; o < 256; o <<= 1) {
        int y = (tid >= o) ? lscan[tid - o] : 0;
        __syncthreads();
        lscan[tid] += y;
        __syncthreads();
    }
    int excl = lscan[tid] - v;
    loff[tid] = excl;
    const int base = bbase[b];
    if (tid < nn) {
        cnt[nlo + tid]  = v;
        off[nlo + tid]  = base + excl;
        dinv[nlo + tid] = rsqrtf((float)v + 1.0f);
    }
    lcnt[tid] = 0;
    __syncthreads();
    // pass 2: place source ids
    if (ke <= CAPB) {
        for (int k = tid; k < ke; k += 256) {
            int p  = src[k];
            int li = ((unsigned)p) >> 24;
            int q  = atomicAdd(&lcnt[li], 1);
            stage[loff[li] + q] = p & 0x00FFFFFF;
        }
        __syncthreads();
        for (int s = tid; s < ke; s += 256) sedge[base + s] = stage[s];
    } else {   // statistically impossible overflow fallback
        for (int k = tid; k < ke; k += 256) {
            int p  = src[k];
            int li = ((unsigned)p) >> 24;
            int q  = atomicAdd(&lcnt[li], 1);
            sedge[base + loff[li] + q] = p & 0x00FFFFFF;
        }
    }
}

// ------------------------- fused: layer-1 aggregate + relu + layer-2 dots ---
// 4 nodes per wave (one per 16-lane group); lane owns features l16*4..+3.
__global__ __launch_bounds__(256) void k_fused(
    const int* __restrict__ off, const int* __restrict__ cnt,
    const int* __restrict__ sedge, const float* __restrict__ dinv,
    const _Float16* __restrict__ xwh,
    const float* __restrict__ b1, const float* __restrict__ bf1,
    const float* __restrict__ W2, const float* __restrict__ Wf2,
    const float* __restrict__ b2, const float* __restrict__ bf2,
    float* __restrict__ z, float* __restrict__ out, int N)
{
    const int wv   = (blockIdx.x * blockDim.x + threadIdx.x) >> 6;  // wave id
    const int lane = threadIdx.x & 63;
    const int g    = lane >> 4;        // node slot 0..3
    const int l16  = lane & 15;        // feature quad: features l16*4..+3
    int i = wv * 4 + g;
    const bool ok = (i < N);
    i = ok ? i : (N - 1);

    const int jb  = off[i];
    const int deg = cnt[i];
    const float di = dinv[i];

    float4 acc = make_float4(0.f, 0.f, 0.f, 0.f);
    int j = 0;
    for (; j + 4 <= deg; j += 4) {   // 4 gathers in flight per group
        int r0 = sedge[jb + j];
        int r1 = sedge[jb + j + 1];
        int r2 = sedge[jb + j + 2];
        int r3 = sedge[jb + j + 3];
        float s0 = dinv[r0] * di;
        float s1 = dinv[r1] * di;
        float s2 = dinv[r2] * di;
        float s3 = dinv[r3] * di;
        half4v a0 = *(const half4v*)(xwh + (size_t)r0 * FIN + l16 * 4);
        half4v a1 = *(const half4v*)(xwh + (size_t)r1 * FIN + l16 * 4);
        half4v a2 = *(const half4v*)(xwh + (size_t)r2 * FIN + l16 * 4);
        half4v a3 = *(const half4v*)(xwh + (size_t)r3 * FIN + l16 * 4);
        acc.x = fmaf((float)a0[0], s0, acc.x);
        acc.y = fmaf((float)a0[1], s0, acc.y);
        acc.z = fmaf((float)a0[2], s0, acc.z);
        acc.w = fmaf((float)a0[3], s0, acc.w);
        acc.x = fmaf((float)a1[0], s1, acc.x);
        acc.y = fmaf((float)a1[1], s1, acc.y);
        acc.z = fmaf((float)a1[2], s1, acc.z);
        acc.w = fmaf((float)a1[3], s1, acc.w);
        acc.x = fmaf((float)a2[0], s2, acc.x);
        acc.y = fmaf((float)a2[1], s2, acc.y);
        acc.z = fmaf((float)a2[2], s2, acc.z);
        acc.w = fmaf((float)a2[3], s2, acc.w);
        acc.x = fmaf((float)a3[0], s3, acc.x);
        acc.y = fmaf((float)a3[1], s3, acc.y);
        acc.z = fmaf((float)a3[2], s3, acc.z);
        acc.w = fmaf((float)a3[3], s3, acc.w);
    }
    for (; j < deg; ++j) {
        int r = sedge[jb + j];
        float s = dinv[r] * di;
        half4v a = *(const half4v*)(xwh + (size_t)r * FIN + l16 * 4);
        acc.x = fmaf((float)a[0], s, acc.x);
        acc.y = fmaf((float)a[1], s, acc.y);
        acc.z = fmaf((float)a[2], s, acc.z);
        acc.w = fmaf((float)a[3], s, acc.w);
    }

    // self loop (fp16 row)
    float dd = di * di;
    half4v svh = *(const half4v*)(xwh + (size_t)i * FIN + l16 * 4);
    acc.x = fmaf((float)svh[0], dd, acc.x);
    acc.y = fmaf((float)svh[1], dd, acc.y);
    acc.z = fmaf((float)svh[2], dd, acc.z);
    acc.w = fmaf((float)svh[3], dd, acc.w);

    // epilogue: relu + two 128-dots (weights l16-indexed: shared by 4 nodes)
    float4 b1v  = *(const float4*)(b1  + l16 * 4);
    float4 bf1v = *(const float4*)(bf1 + l16 * 4);
    half4v x1h  = *(const half4v*)(xwh + (size_t)i * FIN + HH + l16 * 4);
    float4 h0, h1;
    h0.x = fmaxf(acc.x + b1v.x, 0.f);  h0.y = fmaxf(acc.y + b1v.y, 0.f);
    h0.z = fmaxf(acc.z + b1v.z, 0.f);  h0.w = fmaxf(acc.w + b1v.w, 0.f);
    h1.x = fmaxf((float)x1h[0] + bf1v.x, 0.f);  h1.y = fmaxf((float)x1h[1] + bf1v.y, 0.f);
    h1.z = fmaxf((float)x1h[2] + bf1v.z, 0.f);  h1.w = fmaxf((float)x1h[3] + bf1v.w, 0.f);

    float4 w2a  = *(const float4*)(W2  + l16 * 4);
    float4 w2b  = *(const float4*)(W2  + HH + l16 * 4);
    float4 wf2a = *(const float4*)(Wf2 + l16 * 4);
    float4 wf2b = *(const float4*)(Wf2 + HH + l16 * 4);

    float zp = h0.x * w2a.x + h0.y * w2a.y + h0.z * w2a.z + h0.w * w2a.w
             + h1.x * w2b.x + h1.y * w2b.y + h1.z * w2b.z + h1.w * w2b.w;
    float fp = h0.x * wf2a.x + h0.y * wf2a.y + h0.z * wf2a.z + h0.w * wf2a.w
             + h1.x * wf2b.x + h1.y * wf2b.y + h1.z * wf2b.z + h1.w * wf2b.w;
#pragma unroll
    for (int o = 8; o > 0; o >>= 1) {
        zp += __shfl_xor(zp, o, 16);   // reduce within the 16-lane group
        fp += __shfl_xor(fp, o, 16);
    }
    if (l16 == 0 && ok) {
        z[i]   = zp;
        out[i] = fp + b2[0] + bf2[0];
    }
}

// ------------------------------------------- layer-2 aggregate (CSR) --------
// out[i] += di * ( sum_j z[r_j]*dinv[r_j]  +  z[i]*di )
__global__ __launch_bounds__(256) void k_agg2(
    const int* __restrict__ off, const int* __restrict__ cnt,
    const int* __restrict__ sedge, const float* __restrict__ dinv,
    const float* __restrict__ z, float* __restrict__ out, int N)
{
    const int wid  = (blockIdx.x * blockDim.x + threadIdx.x) >> 6;
    const int lane = threadIdx.x & 63;
    const int g    = lane >> 4;
    const int l16  = lane & 15;
    int i = wid * 4 + g;
    bool ok = (i < N);
    i = ok ? i : (N - 1);

    const int jb = off[i], je = jb + cnt[i];
    float s = 0.0f;
    for (int j = jb + l16; j < je; j += 16) {
        int r = sedge[j];
        s = fmaf(z[r], dinv[r], s);
    }
#pragma unroll
    for (int o = 8; o > 0; o >>= 1) s += __shfl_xor(s, o, 64);
    if (l16 == 0 && ok) {
        float di = dinv[i];
        out[i] += di * fmaf(z[i], di, s);
    }
}

// ---------------------------------------------------------------- launch ----
extern "C" void kernel_launch(void* const* d_in, const int* in_sizes, int n_in,
                              void* d_out, int out_size, void* d_ws, size_t ws_size,
                              hipStream_t stream)
{
    const float* x   = (const float*)d_in[0];
    const int*   ei  = (const int*)d_in[1];    // [2,E]: row=ei[e], col=ei[E+e]
    const float* W1  = (const float*)d_in[2];
    const float* b1  = (const float*)d_in[3];
    const float* Wf1 = (const float*)d_in[4];
    const float* bf1 = (const float*)d_in[5];
    const float* W2  = (const float*)d_in[6];
    const float* b2  = (const float*)d_in[7];
    const float* Wf2 = (const float*)d_in[8];
    const float* bf2 = (const float*)d_in[9];

    const int N = in_sizes[0] / FIN;   // 100000
    const int E = in_sizes[1] / 2;     // 1600000
    const int NB = (N + NPB - 1) / NPB;  // 391 buckets
    float* out = (float*)d_out;

    // workspace layout (4-byte units):
    // dinv[N] | z[N] | cnt[N] | bcur[MAXNB] | bbase[MAXNB] | off[N] |
    // sedge int[E] | xwh[N*128 halves] | binned int[NB*BCAP]
    float* ws   = (float*)d_ws;
    float* dinv = ws;
    float* z    = dinv + N;
    int*   cnt  = (int*)(z + N);
    int*   bcur = cnt + N;
    int*   bbase = bcur + MAXNB;
    int*   off  = bbase + MAXNB;
    int*   sedge = off + N;
    _Float16* xwh = (_Float16*)(sedge + E);
    int*   binned = (int*)(xwh + (size_t)N * FIN);

    hipMemsetAsync(bcur, 0, (size_t)MAXNB * sizeof(int), stream);

    {
        int nbin  = (E + BCH - 1) / BCH;       // 391 bin blocks
        int ngemm = (N + 63) / 64;             // 1563 gemm blocks
        k_bingemm<<<nbin + ngemm, 256, 0, stream>>>(
            ei, bcur, binned, E, NB, nbin, x, W1, Wf1, xwh, N);
    }

    k_bscan<<<1, 256, 0, stream>>>(bcur, bbase, NB);
    k_place<<<NB, 256, 0, stream>>>(binned, bcur, bbase, cnt, off, dinv, sedge, N);

    {
        long waves = ((long)N + 3) / 4;        // one wave per 4 nodes
        int blocks = (int)((waves * 64 + 255) / 256);
        k_fused<<<blocks, 256, 0, stream>>>(off, cnt, sedge, dinv, xwh,
                                            b1, bf1, W2, Wf2, b2, bf2, z, out, N);
    }

    {
        long waves = ((long)N + 3) / 4;        // one wave per 4 nodes
        int blocks = (int)((waves * 64 + 255) / 256);
        k_agg2<<<blocks, 256, 0, stream>>>(off, cnt, sedge, dinv, z, out, N);
    }
}

// Round 22
// 200.623 us; speedup vs baseline: 1.2614x; 1.0293x over previous
//
#include <hip/hip_runtime.h>
#include <hip/hip_fp16.h>

constexpr int FIN   = 128;   // input features (also total hidden width)
constexpr int HH    = 64;    // half hidden (GCN branch width)
constexpr int NPB   = 256;   // nodes per bucket (bucket = col >> 8)
constexpr int MAXNB = 512;   // max buckets supported (N <= 131072)
constexpr int BCH   = 4096;  // edges per bin block
constexpr int BCAP  = 4608;  // bucket stride in binned[]
constexpr int CAPB  = 4500;  // LDS stage capacity in k_place

constexpr int SMEM_BYTES = BCH * 8 + 4 * MAXNB * 4 + 256 * 4;

typedef _Float16 half4v __attribute__((ext_vector_type(4)));
typedef _Float16 half8v __attribute__((ext_vector_type(8)));
typedef float    f32x4 __attribute__((ext_vector_type(4)));

// ------------------- merged: CSR bin (blocks < nbin) + MFMA GEMM (rest) -----
__global__ __launch_bounds__(256) void k_bingemm(
    const int* __restrict__ ei, int* __restrict__ bcur,
    int* __restrict__ binned, int E, int NB, int nbin,
    const float* __restrict__ x, const float* __restrict__ W1,
    const float* __restrict__ Wf1, _Float16* __restrict__ xwh, int N)
{
    __shared__ __align__(16) char smem[SMEM_BYTES];
    const int tid = threadIdx.x;

    if (blockIdx.x < nbin) {
        // ---------------- bin role: bucket-sort edge chunk into binned[] ----
        int2* st   = (int2*)smem;
        int* hist  = (int*)(smem + BCH * 8);
        int* scur  = hist + MAXNB;
        int* gbase = scur + MAXNB;
        int* sbase = gbase + MAXNB;
        int* ssum  = sbase + MAXNB;

        const int e0 = blockIdx.x * BCH;
        const int nE = min(BCH, E - e0);

        for (int b = tid; b < NB; b += 256) hist[b] = 0;
        __syncthreads();

        for (int k = tid; k < nE; k += 256)
            atomicAdd(&hist[ei[E + e0 + k] >> 8], 1);
        __syncthreads();

        // exclusive scan hist -> sbase (2 elems/thread over padded 512)
        int h0 = (2 * tid     < NB) ? hist[2 * tid]     : 0;
        int h1 = (2 * tid + 1 < NB) ? hist[2 * tid + 1] : 0;
        ssum[tid] = h0 + h1;
        __syncthreads();
        for (int o = 1; o < 256; o <<= 1) {
            int y = (tid >= o) ? ssum[tid - o] : 0;
            __syncthreads();
            ssum[tid] += y;
            __syncthreads();
        }
        int eb = ssum[tid] - h0 - h1;
        if (2 * tid     < NB) { sbase[2 * tid]     = eb;      scur[2 * tid]     = eb; }
        if (2 * tid + 1 < NB) { sbase[2 * tid + 1] = eb + h0; scur[2 * tid + 1] = eb + h0; }
        __syncthreads();

        // claim global per-bucket ranges (one atomic per non-empty bucket)
        for (int b = tid; b < NB; b += 256)
            if (hist[b] > 0) gbase[b] = atomicAdd(bcur + b, hist[b]);

        // LDS reorder by bucket
        for (int k = tid; k < nE; k += 256) {
            int r = ei[e0 + k];
            int c = ei[E + e0 + k];
            int s = atomicAdd(&scur[c >> 8], 1);
            st[s] = make_int2(r, c);
        }
        __syncthreads();

        // coalesced-run flush (entry packed: (li<<24)|r)
        for (int s = tid; s < nE; s += 256) {
            int2 rc = st[s];
            int b = rc.y >> 8;
            long dest = (long)b * BCAP + gbase[b] + (s - sbase[b]);
            binned[dest] = ((rc.y & 255) << 24) | rc.x;
        }
    } else {
        // ---------------- gemm role: xwh[N,128] = fp16(x @ [W1|Wf1]) --------
        _Float16* wt = (_Float16*)smem;      // wt[n][k] swizzled, 32KB

        for (int idx = tid; idx < 128 * 128; idx += 256) {
            int n = idx & 127, k = idx >> 7;
            float v = (n < HH) ? W1[k * HH + n] : Wf1[k * HH + (n - HH)];
            int g  = k >> 3, j = k & 7;
            int pg = g ^ (n & 7);            // bank swizzle
            wt[n * 128 + pg * 8 + j] = (_Float16)v;
        }
        __syncthreads();

        const int w  = tid >> 6;             // wave 0..3
        const int l  = tid & 63;
        const int rb = (blockIdx.x - nbin) * 64 + w * 16;

        int arow = rb + (l & 15);
        arow = (arow < N) ? arow : (N - 1);
        half8v af[4];
#pragma unroll
        for (int ks = 0; ks < 4; ++ks) {
            const float* src = x + (size_t)arow * FIN + ks * 32 + (l >> 4) * 8;
            float4 x0 = *(const float4*)(src);
            float4 x1 = *(const float4*)(src + 4);
            half8v a;
            a[0] = (_Float16)x0.x; a[1] = (_Float16)x0.y;
            a[2] = (_Float16)x0.z; a[3] = (_Float16)x0.w;
            a[4] = (_Float16)x1.x; a[5] = (_Float16)x1.y;
            a[6] = (_Float16)x1.z; a[7] = (_Float16)x1.w;
            af[ks] = a;
        }

        const int orow0 = rb + (l >> 4) * 4;
#pragma unroll
        for (int c = 0; c < 8; ++c) {
            f32x4 acc = {0.f, 0.f, 0.f, 0.f};
            const int n = (l & 15) + c * 16;
#pragma unroll
            for (int ks = 0; ks < 4; ++ks) {
                int g  = ks * 4 + (l >> 4);
                int pg = g ^ (n & 7);
                half8v bf = *(const half8v*)(wt + n * 128 + pg * 8);
                acc = __builtin_amdgcn_mfma_f32_16x16x32_f16(af[ks], bf, acc, 0, 0, 0);
            }
            const int ocol = c * 16 + (l & 15);
#pragma unroll
            for (int r = 0; r < 4; ++r) {
                int orow = orow0 + r;
                if (orow < N)
                    xwh[(size_t)orow * FIN + ocol] = (_Float16)acc[r];
            }
        }
    }
}

// ---------------- pass B: per-bucket degree+scan+place, coalesced write -----
// bbase computed inline (prefix over L2-resident bcur[0..b)) — k_bscan gone.
__global__ __launch_bounds__(256) void k_place(
    const int* __restrict__ binned, const int* __restrict__ bcur,
    int* __restrict__ cnt, int* __restrict__ off,
    float* __restrict__ dinv, int* __restrict__ sedge, int N)
{
    const int b   = blockIdx.x;
    const int tid = threadIdx.x;
    const int nlo = b << 8;
    const int nn  = min(NPB, N - nlo);
    __shared__ int lcnt[NPB], loff[NPB], lscan[NPB];
    __shared__ int stage[CAPB];

    // inline bucket base: sum of bcur[0..b)
    int part = 0;
    for (int k = tid; k < b; k += 256) part += bcur[k];
    lscan[tid] = part;
    __syncthreads();
    for (int o = 128; o > 0; o >>= 1) {
        if (tid < o) lscan[tid] += lscan[tid + o];
        __syncthreads();
    }
    const int base = lscan[0];
    __syncthreads();

    lcnt[tid] = 0;
    __syncthreads();
    const int ke = bcur[b];
    const int* src = binned + (long)b * BCAP;
    // pass 1: per-node degree (li = packed>>24)
    for (int k = tid; k < ke; k += 256)
        atomicAdd(&lcnt[((unsigned)src[k]) >> 24], 1);
    __syncthreads();
    // exclusive scan of lcnt[256]
    int v = lcnt[tid];
    lscan[tid] = v;
    __syncthreads();
    for (int o = 1; o < 256; o <<= 1) {
        int y = (tid >= o) ? lscan[tid - o] : 0;
        __syncthreads();
        lscan[tid] += y;
        __syncthreads();
    }
    int excl = lscan[tid] - v;
    loff[tid] = excl;
    if (tid < nn) {
        cnt[nlo + tid]  = v;
        off[nlo + tid]  = base + excl;
        dinv[nlo + tid] = rsqrtf((float)v + 1.0f);
    }
    lcnt[tid] = 0;
    __syncthreads();
    // pass 2: place source ids
    if (ke <= CAPB) {
        for (int k = tid; k < ke; k += 256) {
            int p  = src[k];
            int li = ((unsigned)p) >> 24;
            int q  = atomicAdd(&lcnt[li], 1);
            stage[loff[li] + q] = p & 0x00FFFFFF;
        }
        __syncthreads();
        for (int s = tid; s < ke; s += 256) sedge[base + s] = stage[s];
    } else {   // statistically impossible overflow fallback
        for (int k = tid; k < ke; k += 256) {
            int p  = src[k];
            int li = ((unsigned)p) >> 24;
            int q  = atomicAdd(&lcnt[li], 1);
            sedge[base + loff[li] + q] = p & 0x00FFFFFF;
        }
    }
}

// ------------------------- fused: layer-1 aggregate + relu + layer-2 dots ---
// 4 nodes per wave; lane owns features l16*4..+3. Stores zd[i] = z[i]*dinv[i]
// so k_agg2 needs only ONE gather per edge (was z[r] + dinv[r]).
__global__ __launch_bounds__(256) void k_fused(
    const int* __restrict__ off, const int* __restrict__ cnt,
    const int* __restrict__ sedge, const float* __restrict__ dinv,
    const _Float16* __restrict__ xwh,
    const float* __restrict__ b1, const float* __restrict__ bf1,
    const float* __restrict__ W2, const float* __restrict__ Wf2,
    const float* __restrict__ b2, const float* __restrict__ bf2,
    float* __restrict__ zd, float* __restrict__ out, int N)
{
    const int wv   = (blockIdx.x * blockDim.x + threadIdx.x) >> 6;  // wave id
    const int lane = threadIdx.x & 63;
    const int g    = lane >> 4;        // node slot 0..3
    const int l16  = lane & 15;        // feature quad: features l16*4..+3
    int i = wv * 4 + g;
    const bool ok = (i < N);
    i = ok ? i : (N - 1);

    const int jb  = off[i];
    const int deg = cnt[i];
    const float di = dinv[i];

    float4 acc = make_float4(0.f, 0.f, 0.f, 0.f);
    int j = 0;
    for (; j + 4 <= deg; j += 4) {   // 4 gathers in flight per group
        int r0 = sedge[jb + j];
        int r1 = sedge[jb + j + 1];
        int r2 = sedge[jb + j + 2];
        int r3 = sedge[jb + j + 3];
        float s0 = dinv[r0] * di;
        float s1 = dinv[r1] * di;
        float s2 = dinv[r2] * di;
        float s3 = dinv[r3] * di;
        half4v a0 = *(const half4v*)(xwh + (size_t)r0 * FIN + l16 * 4);
        half4v a1 = *(const half4v*)(xwh + (size_t)r1 * FIN + l16 * 4);
        half4v a2 = *(const half4v*)(xwh + (size_t)r2 * FIN + l16 * 4);
        half4v a3 = *(const half4v*)(xwh + (size_t)r3 * FIN + l16 * 4);
        acc.x = fmaf((float)a0[0], s0, acc.x);
        acc.y = fmaf((float)a0[1], s0, acc.y);
        acc.z = fmaf((float)a0[2], s0, acc.z);
        acc.w = fmaf((float)a0[3], s0, acc.w);
        acc.x = fmaf((float)a1[0], s1, acc.x);
        acc.y = fmaf((float)a1[1], s1, acc.y);
        acc.z = fmaf((float)a1[2], s1, acc.z);
        acc.w = fmaf((float)a1[3], s1, acc.w);
        acc.x = fmaf((float)a2[0], s2, acc.x);
        acc.y = fmaf((float)a2[1], s2, acc.y);
        acc.z = fmaf((float)a2[2], s2, acc.z);
        acc.w = fmaf((float)a2[3], s2, acc.w);
        acc.x = fmaf((float)a3[0], s3, acc.x);
        acc.y = fmaf((float)a3[1], s3, acc.y);
        acc.z = fmaf((float)a3[2], s3, acc.z);
        acc.w = fmaf((float)a3[3], s3, acc.w);
    }
    for (; j < deg; ++j) {
        int r = sedge[jb + j];
        float s = dinv[r] * di;
        half4v a = *(const half4v*)(xwh + (size_t)r * FIN + l16 * 4);
        acc.x = fmaf((float)a[0], s, acc.x);
        acc.y = fmaf((float)a[1], s, acc.y);
        acc.z = fmaf((float)a[2], s, acc.z);
        acc.w = fmaf((float)a[3], s, acc.w);
    }

    // self loop (fp16 row)
    float dd = di * di;
    half4v svh = *(const half4v*)(xwh + (size_t)i * FIN + l16 * 4);
    acc.x = fmaf((float)svh[0], dd, acc.x);
    acc.y = fmaf((float)svh[1], dd, acc.y);
    acc.z = fmaf((float)svh[2], dd, acc.z);
    acc.w = fmaf((float)svh[3], dd, acc.w);

    // epilogue: relu + two 128-dots (weights l16-indexed: shared by 4 nodes)
    float4 b1v  = *(const float4*)(b1  + l16 * 4);
    float4 bf1v = *(const float4*)(bf1 + l16 * 4);
    half4v x1h  = *(const half4v*)(xwh + (size_t)i * FIN + HH + l16 * 4);
    float4 h0, h1;
    h0.x = fmaxf(acc.x + b1v.x, 0.f);  h0.y = fmaxf(acc.y + b1v.y, 0.f);
    h0.z = fmaxf(acc.z + b1v.z, 0.f);  h0.w = fmaxf(acc.w + b1v.w, 0.f);
    h1.x = fmaxf((float)x1h[0] + bf1v.x, 0.f);  h1.y = fmaxf((float)x1h[1] + bf1v.y, 0.f);
    h1.z = fmaxf((float)x1h[2] + bf1v.z, 0.f);  h1.w = fmaxf((float)x1h[3] + bf1v.w, 0.f);

    float4 w2a  = *(const float4*)(W2  + l16 * 4);
    float4 w2b  = *(const float4*)(W2  + HH + l16 * 4);
    float4 wf2a = *(const float4*)(Wf2 + l16 * 4);
    float4 wf2b = *(const float4*)(Wf2 + HH + l16 * 4);

    float zp = h0.x * w2a.x + h0.y * w2a.y + h0.z * w2a.z + h0.w * w2a.w
             + h1.x * w2b.x + h1.y * w2b.y + h1.z * w2b.z + h1.w * w2b.w;
    float fp = h0.x * wf2a.x + h0.y * wf2a.y + h0.z * wf2a.z + h0.w * wf2a.w
             + h1.x * wf2b.x + h1.y * wf2b.y + h1.z * wf2b.z + h1.w * wf2b.w;
#pragma unroll
    for (int o = 8; o > 0; o >>= 1) {
        zp += __shfl_xor(zp, o, 16);   // reduce within the 16-lane group
        fp += __shfl_xor(fp, o, 16);
    }
    if (l16 == 0 && ok) {
        zd[i]  = zp * di;              // pre-scaled for layer-2 aggregate
        out[i] = fp + b2[0] + bf2[0];
    }
}

// ------------------------------------------- layer-2 aggregate (CSR) --------
// out[i] += di * ( sum_j zd[r_j] + zd[i] )   with zd[x] = z[x]*dinv[x]
__global__ __launch_bounds__(256) void k_agg2(
    const int* __restrict__ off, const int* __restrict__ cnt,
    const int* __restrict__ sedge, const float* __restrict__ dinv,
    const float* __restrict__ zd, float* __restrict__ out, int N)
{
    const int wid  = (blockIdx.x * blockDim.x + threadIdx.x) >> 6;
    const int lane = threadIdx.x & 63;
    const int g    = lane >> 4;
    const int l16  = lane & 15;
    int i = wid * 4 + g;
    bool ok = (i < N);
    i = ok ? i : (N - 1);

    const int jb = off[i], je = jb + cnt[i];
    float s = 0.0f;
    for (int j = jb + l16; j < je; j += 16)
        s += zd[sedge[j]];
#pragma unroll
    for (int o = 8; o > 0; o >>= 1) s += __shfl_xor(s, o, 64);
    if (l16 == 0 && ok) {
        out[i] += dinv[i] * (s + zd[i]);
    }
}

// ---------------------------------------------------------------- launch ----
extern "C" void kernel_launch(void* const* d_in, const int* in_sizes, int n_in,
                              void* d_out, int out_size, void* d_ws, size_t ws_size,
                              hipStream_t stream)
{
    const float* x   = (const float*)d_in[0];
    const int*   ei  = (const int*)d_in[1];    // [2,E]: row=ei[e], col=ei[E+e]
    const float* W1  = (const float*)d_in[2];
    const float* b1  = (const float*)d_in[3];
    const float* Wf1 = (const float*)d_in[4];
    const float* bf1 = (const float*)d_in[5];
    const float* W2  = (const float*)d_in[6];
    const float* b2  = (const float*)d_in[7];
    const float* Wf2 = (const float*)d_in[8];
    const float* bf2 = (const float*)d_in[9];

    const int N = in_sizes[0] / FIN;   // 100000
    const int E = in_sizes[1] / 2;     // 1600000
    const int NB = (N + NPB - 1) / NPB;  // 391 buckets
    float* out = (float*)d_out;

    // workspace layout (4-byte units):
    // dinv[N] | zd[N] | cnt[N] | bcur[MAXNB] | bbase(pad) | off[N] |
    // sedge int[E] | xwh[N*128 halves] | binned int[NB*BCAP]
    float* ws   = (float*)d_ws;
    float* dinv = ws;
    float* zd   = dinv + N;
    int*   cnt  = (int*)(zd + N);
    int*   bcur = cnt + N;
    int*   off  = bcur + 2 * MAXNB;
    int*   sedge = off + N;
    _Float16* xwh = (_Float16*)(sedge + E);
    int*   binned = (int*)(xwh + (size_t)N * FIN);

    hipMemsetAsync(bcur, 0, (size_t)MAXNB * sizeof(int), stream);

    {
        int nbin  = (E + BCH - 1) / BCH;       // 391 bin blocks
        int ngemm = (N + 63) / 64;             // 1563 gemm blocks
        k_bingemm<<<nbin + ngemm, 256, 0, stream>>>(
            ei, bcur, binned, E, NB, nbin, x, W1, Wf1, xwh, N);
    }

    k_place<<<NB, 256, 0, stream>>>(binned, bcur, cnt, off, dinv, sedge, N);

    {
        long waves = ((long)N + 3) / 4;        // one wave per 4 nodes
        int blocks = (int)((waves * 64 + 255) / 256);
        k_fused<<<blocks, 256, 0, stream>>>(off, cnt, sedge, dinv, xwh,
                                            b1, bf1, W2, Wf2, b2, bf2, zd, out, N);
    }

    {
        long waves = ((long)N + 3) / 4;        // one wave per 4 nodes
        int blocks = (int)((waves * 64 + 255) / 256);
        k_agg2<<<blocks, 256, 0, stream>>>(off, cnt, sedge, dinv, zd, out, N);
    }
}